// Round 12
// baseline (326.822 us; speedup 1.0000x reference)
//
#include <hip/hip_runtime.h>
#include <hip/hip_bf16.h>
#include <stdint.h>

// SelfAttLogn: B=8 T=2048 DM=1024 H=16 DH=64, LOG_LEN=11
// convert x | transpose W | QKV gemm (r8: 256^2 8-phase raw-barrier) | spanmax(q only)
// | spanv (fused span attention + k-max hierarchy) | spancomb | merge | out gemm

typedef unsigned short u16;
typedef __attribute__((ext_vector_type(8))) short bf16x8;
typedef __attribute__((ext_vector_type(4))) float f32x4;

#define B_ 8
#define T_ 2048
#define H_ 16
#define DHD 64
#define LOGL 11

// span row offsets per level (rows of 64 elems), head-major: row = LO[l-1] + bh*n_l + m
__device__ constexpr unsigned LO[10] = {0u,131072u,196608u,229376u,245760u,
                                        253952u,258048u,260096u,261120u,261632u};

__device__ __forceinline__ float b2f(u16 u){
  union { float f; unsigned int i; } x; x.i = ((unsigned int)u) << 16; return x.f;
}
__device__ __forceinline__ float bl(unsigned u){
  union { float f; unsigned int i; } x; x.i = u << 16; return x.f;
}
__device__ __forceinline__ float bh(unsigned u){
  union { float f; unsigned int i; } x; x.i = u & 0xffff0000u; return x.f;
}
__device__ __forceinline__ u16 f2b(float f){
  union { float f; unsigned int i; } x; x.f = f;
  unsigned int r = x.i + 0x7fffu + ((x.i >> 16) & 1u);
  return (u16)(r >> 16);
}
__device__ __forceinline__ void up8(uint4 v, float* f){
  f[0]=bl(v.x); f[1]=bh(v.x); f[2]=bl(v.y); f[3]=bh(v.y);
  f[4]=bl(v.z); f[5]=bh(v.z); f[6]=bl(v.w); f[7]=bh(v.w);
}
__device__ __forceinline__ uint4 pk8(const float* f){
  uint4 o; u16* p=(u16*)&o;
  #pragma unroll
  for (int i=0;i<8;i++) p[i]=f2b(f[i]);
  return o;
}
__device__ __forceinline__ void cp8(float* a, const float* b){
  #pragma unroll
  for (int i=0;i<8;i++) a[i]=b[i];
}
__device__ __forceinline__ void mx8(float* a, const float* b){
  #pragma unroll
  for (int i=0;i<8;i++) a[i]=fmaxf(a[i],b[i]);
}
__device__ __forceinline__ void fma8(float* fa, float w, uint4 v){
  fa[0]+=w*bl(v.x); fa[1]+=w*bh(v.x); fa[2]+=w*bl(v.y); fa[3]+=w*bh(v.y);
  fa[4]+=w*bl(v.z); fa[5]+=w*bh(v.z); fa[6]+=w*bl(v.w); fa[7]+=w*bh(v.w);
}
__device__ __forceinline__ float dotrow(const float* kreg, const u16* sp){
  float d = 0.f;
  #pragma unroll
  for (int c=0;c<8;c++){
    uint4 t4 = *(const uint4*)(sp + c*8);
    d += kreg[c*8+0]*bl(t4.x) + kreg[c*8+1]*bh(t4.x)
       + kreg[c*8+2]*bl(t4.y) + kreg[c*8+3]*bh(t4.y)
       + kreg[c*8+4]*bl(t4.z) + kreg[c*8+5]*bh(t4.z)
       + kreg[c*8+6]*bl(t4.w) + kreg[c*8+7]*bh(t4.w);
  }
  return d;
}
__device__ __forceinline__ void gload_lds16(const void* g, void* l) {
  __builtin_amdgcn_global_load_lds((const __attribute__((address_space(1))) void*)g,
                                   (__attribute__((address_space(3))) void*)l, 16, 0, 0);
}

// raw HW barrier; VMW carries the memory clobber so LDS reads can't hoist past gates
#define BARRIER() __builtin_amdgcn_s_barrier()
#define VMW(N) asm volatile("s_waitcnt vmcnt(" #N ")" ::: "memory")

// ---------------- convert x to bf16 ----------------
__global__ __launch_bounds__(256) void convert_x_kernel(
    const float* __restrict__ x, u16* __restrict__ xb)
{
  size_t i = ((size_t)blockIdx.x*256 + threadIdx.x)*8;
  float4 a = *(const float4*)(x+i);
  float4 b = *(const float4*)(x+i+4);
  u16 o[8] = {f2b(a.x),f2b(a.y),f2b(a.z),f2b(a.w),f2b(b.x),f2b(b.y),f2b(b.z),f2b(b.w)};
  *(uint4*)(xb+i) = *(uint4*)o;
}

// ---------------- transpose-convert weights ----------------
__global__ __launch_bounds__(256) void wtrans_kernel(
    const float* __restrict__ w0, const float* __restrict__ w1,
    const float* __restrict__ w2, const float* __restrict__ w3,
    u16* __restrict__ wqkvT, u16* __restrict__ woT)
{
  __shared__ u16 tile[64][65];
  int mat = blockIdx.z;
  const float* src = (mat==0)?w0:(mat==1)?w1:(mat==2)?w2:w3;
  u16* dst = (mat<3) ? (wqkvT + (size_t)mat*1048576ull) : woT;
  int r0 = blockIdx.y*64, c0 = blockIdx.x*64;
  int t = threadIdx.x;
  int tr = t>>4, tc = (t&15)*4;
  #pragma unroll
  for (int i=0;i<4;i++){
    int r = tr + i*16;
    float4 a = *(const float4*)(src + (size_t)(r0+r)*1024 + c0 + tc);
    tile[tc+0][r] = f2b(a.x);
    tile[tc+1][r] = f2b(a.y);
    tile[tc+2][r] = f2b(a.z);
    tile[tc+3][r] = f2b(a.w);
  }
  __syncthreads();
  #pragma unroll
  for (int i=0;i<4;i++){
    int rr = tr + i*16;
    uint2 o; u16* p = (u16*)&o;
    p[0]=tile[rr][tc+0]; p[1]=tile[rr][tc+1]; p[2]=tile[rr][tc+2]; p[3]=tile[rr][tc+3];
    *(uint2*)(dst + (size_t)(c0+rr)*1024 + r0 + tc) = o;
  }
}

// ---------------- 256^2 8-phase bf16 GEMM (round-8 exact: best measured) --------
#define MF16(AF, BF, MB, NB)                                                \
  _Pragma("unroll") for (int mi=0;mi<4;++mi)                                \
  _Pragma("unroll") for (int nj=0;nj<2;++nj)                                \
  _Pragma("unroll") for (int kk=0;kk<2;++kk)                                \
    acc[(MB)+mi][(NB)+nj] = __builtin_amdgcn_mfma_f32_16x16x32_bf16(        \
        AF[mi][kk], BF[nj][kk], acc[(MB)+mi][(NB)+nj], 0, 0, 0)

#define TILE_STEP(BUF, S1T,S1H, S2T,S2H, S3T,S3H, S4T,S4H, VN)              \
  do {                                                                      \
    _Pragma("unroll") for (int mi=0;mi<4;++mi)                              \
      _Pragma("unroll") for (int kk=0;kk<2;++kk)                            \
        afr[mi][kk] = ldsA(BUF, mi, kk);                                    \
    _Pragma("unroll") for (int nj=0;nj<2;++nj)                              \
      _Pragma("unroll") for (int kk=0;kk<2;++kk)                            \
        bfr0[nj][kk] = ldsB(BUF, nj, kk);                                   \
    if ((S1T) >= 0) stage((S1T), (S1H));                                    \
    BARRIER();                                                              \
    __builtin_amdgcn_s_setprio(1);                                          \
    MF16(afr, bfr0, 0, 0);                                                  \
    __builtin_amdgcn_s_setprio(0);                                          \
    BARRIER();                                                              \
    _Pragma("unroll") for (int nj=0;nj<2;++nj)                              \
      _Pragma("unroll") for (int kk=0;kk<2;++kk)                            \
        bfr1[nj][kk] = ldsB(BUF, nj+2, kk);                                 \
    if ((S2T) >= 0) stage((S2T), (S2H));                                    \
    BARRIER();                                                              \
    __builtin_amdgcn_s_setprio(1);                                          \
    MF16(afr, bfr1, 0, 2);                                                  \
    __builtin_amdgcn_s_setprio(0);                                          \
    BARRIER();                                                              \
    _Pragma("unroll") for (int mi=0;mi<4;++mi)                              \
      _Pragma("unroll") for (int kk=0;kk<2;++kk)                            \
        afr[mi][kk] = ldsA(BUF, mi+4, kk);                                  \
    if ((S3T) >= 0) stage((S3T), (S3H));                                    \
    BARRIER();                                                              \
    __builtin_amdgcn_s_setprio(1);                                          \
    MF16(afr, bfr1, 4, 2);                                                  \
    __builtin_amdgcn_s_setprio(0);                                          \
    BARRIER();                                                              \
    _Pragma("unroll") for (int nj=0;nj<2;++nj)                              \
      _Pragma("unroll") for (int kk=0;kk<2;++kk)                            \
        bfr0[nj][kk] = ldsB(BUF, nj, kk);                                   \
    if ((S4T) >= 0) stage((S4T), (S4H));                                    \
    VMW(VN);                                                                \
    BARRIER();                                                              \
    __builtin_amdgcn_s_setprio(1);                                          \
    MF16(afr, bfr0, 4, 0);                                                  \
    __builtin_amdgcn_s_setprio(0);                                          \
    BARRIER();                                                              \
  } while(0)

template<int MODE>
__global__ __launch_bounds__(512, 2) void gemm256_kernel(
    const u16* __restrict__ A, const u16* __restrict__ BT,
    float* __restrict__ C,
    u16* __restrict__ Qp, u16* __restrict__ Kp, u16* __restrict__ Vp,
    int M, int N, int K, int nxtile)
{
  __shared__ __align__(16) u16 As[2][16384];
  __shared__ __align__(16) u16 Bs[2][16384];

  int cpx = gridDim.x >> 3;
  int wg  = blockIdx.x;
  int swz = (wg & 7)*cpx + (wg >> 3);
  const int bx = swz % nxtile, by = swz / nxtile;
  const int m0 = by*256, n0 = bx*256;
  const int tid = threadIdx.x;
  const int lane = tid & 63, w = tid >> 6;
  const int wr = w >> 2, wc = w & 3;

  f32x4 acc[8][4];
  #pragma unroll
  for (int i=0;i<8;i++)
    #pragma unroll
    for (int j=0;j<4;j++) acc[i][j] = (f32x4)0.f;

  auto stage = [&](int t, int h){
    int buf = t & 1;
    int hb  = h & 1;
    bool isA = (h < 2);
    const u16* src = isA ? A : BT;
    int r0g = isA ? m0 : n0;
    u16* lb = isA ? &As[buf][0] : &Bs[buf][0];
    int kb = t*64;
    #pragma unroll
    for (int q = 0; q < 2; ++q) {
      int rit  = hb*128 + q*64 + (tid>>3);
      int colb = ((tid&7)*16) ^ ((rit&7)<<4);
      const u16* g = src + (size_t)(r0g + rit)*K + kb + (colb>>1);
      gload_lds16(g, lb + (hb*128 + q*64)*64 + tid*8);
    }
  };
  auto ldsA = [&](int buf, int mi, int kk)->bf16x8 {
    int r = wr*128 + mi*16 + (lane&15);
    int chunk = (kk*4 + (lane>>4)) ^ (r&7);
    return *(const bf16x8*)&As[buf][r*64 + chunk*8];
  };
  auto ldsB = [&](int buf, int nj, int kk)->bf16x8 {
    int r = wc*64 + nj*16 + (lane&15);
    int chunk = (kk*4 + (lane>>4)) ^ (r&7);
    return *(const bf16x8*)&Bs[buf][r*64 + chunk*8];
  };

  bf16x8 afr[4][2], bfr0[2][2], bfr1[2][2];

  const int NT = K >> 6;                       // 16 for K=1024
  stage(0,0); stage(0,1); stage(0,2); stage(0,3);
  stage(1,0);
  VMW(2);
  BARRIER();

  for (int j = 0; j < NT/2 - 1; ++j) {
    int t1s = 2*j+1, t2s = 2*j+2, t3s = 2*j+3;
    TILE_STEP(0, t1s,1, t1s,2, t1s,3, t2s,0, 2);
    TILE_STEP(1, t2s,1, t2s,2, t2s,3, t3s,0, 2);
  }
  {
    int tl = NT-1;
    TILE_STEP(0, tl,1, tl,2, tl,3, -1,0, 0);
    TILE_STEP(1, -1,0, -1,0, -1,0, -1,0, 0);
  }

  if (MODE == 0) {
    #pragma unroll
    for (int mi=0; mi<8; mi++)
      #pragma unroll
      for (int nj=0; nj<4; nj++){
        int row = m0 + wr*128 + mi*16 + ((lane>>4)<<2);
        int col = n0 + wc*64 + nj*16 + (lane&15);
        #pragma unroll
        for (int r=0;r<4;r++)
          C[(size_t)(row+r)*N + col] = acc[mi][nj][r];
      }
  } else {
    int mat = n0 >> 10;
    u16* dst = (mat==0) ? Qp : (mat==1 ? Kp : Vp);
    float sc = (mat==0) ? 0.125f : 1.0f;
    int cc0 = n0 & 1023;
    #pragma unroll
    for (int mi=0; mi<8; mi++)
      #pragma unroll
      for (int nj=0; nj<4; nj++){
        int row = m0 + wr*128 + mi*16 + ((lane>>4)<<2);
        int col = cc0 + wc*64 + nj*16 + (lane&15);
        #pragma unroll
        for (int r=0;r<4;r++)
          dst[(size_t)(row+r)*1024 + col] = f2b(acc[mi][nj][r]*sc);
      }
  }
}

// ---------------- K1: q-only max hierarchy (sq) ----------------
__global__ __launch_bounds__(256) void spanmax_kernel(
    const u16* __restrict__ qb, u16* __restrict__ sqArr)
{
  __shared__ __align__(16) u16 lsh[63*64];
  int idx = blockIdx.x;                 // 0..255
  int bhh = idx >> 1, half = idx & 1;
  int b = bhh >> 4, h = bhh & 15;
  const u16* src = qb;
  u16* dst = sqArr;
  int tid = threadIdx.x;
  int m5 = tid >> 3, oct = tid & 7;
  int tbase = half*1024 + m5*32;
  unsigned gbase = ((unsigned)(b*2048 + tbase))*1024u + (unsigned)h*64u + (unsigned)oct*8u;

  float c1[8],c2[8],c3[8],c4[8],c5[8],f[8];
  #pragma unroll
  for (int jj=0;jj<32;jj++){
    uint4 v = *(const uint4*)(src + gbase + (unsigned)jj*1024u);
    up8(v,f);
    if ((jj&1)==0) { cp8(c1,f); }
    else {
      mx8(c1,f);
      { unsigned grow = LO[0] + (unsigned)bhh*1024u + (unsigned)((tbase+jj)>>1);
        *(uint4*)(dst + grow*64u + oct*8u) = pk8(c1); }
      if ((jj&3)==1) cp8(c2,c1); else mx8(c2,c1);
      if ((jj&3)==3){
        unsigned grow = LO[1] + (unsigned)bhh*512u + (unsigned)((tbase+jj)>>2);
        *(uint4*)(dst + grow*64u + oct*8u) = pk8(c2);
        if ((jj&7)==3) cp8(c3,c2); else mx8(c3,c2);
        if ((jj&7)==7){
          unsigned g3 = LO[2] + (unsigned)bhh*256u + (unsigned)((tbase+jj)>>3);
          *(uint4*)(dst + g3*64u + oct*8u) = pk8(c3);
          if ((jj&15)==7) cp8(c4,c3); else mx8(c4,c3);
          if ((jj&15)==15){
            unsigned g4 = LO[3] + (unsigned)bhh*128u + (unsigned)((tbase+jj)>>4);
            *(uint4*)(dst + g4*64u + oct*8u) = pk8(c4);
            if (jj==15) cp8(c5,c4); else mx8(c5,c4);
            if (jj==31){
              unsigned g5 = LO[4] + (unsigned)bhh*64u + (unsigned)((tbase+jj)>>5);
              uint4 pk = pk8(c5);
              *(uint4*)(dst + g5*64u + oct*8u) = pk;
              *(uint4*)&lsh[(m5*8+oct)*8] = pk;
            }
          }
        }
      }
    }
  }
  __syncthreads();
  int g = tid>>3;
  #define TREE(LV, INOFF, OUTOFF, NR)                                        \
    if (g < (NR)) {                                                          \
      float a[8], bb[8];                                                     \
      up8(*(const uint4*)&lsh[(((INOFF)+2*g)*8+oct)*8], a);                  \
      up8(*(const uint4*)&lsh[(((INOFF)+2*g+1)*8+oct)*8], bb);               \
      mx8(a,bb);                                                             \
      uint4 pk = pk8(a);                                                     \
      unsigned grow = LO[LV-1] + (unsigned)bhh*(2048u>>LV)                   \
                    + (unsigned)(half*(1024>>LV)) + (unsigned)g;             \
      *(uint4*)(dst + grow*64u + oct*8u) = pk;                               \
      if ((LV)<10) *(uint4*)&lsh[(((OUTOFF)+g)*8+oct)*8] = pk;               \
    }                                                                        \
    __syncthreads();
  TREE(6,0,32,16)
  TREE(7,32,48,8)
  TREE(8,48,56,4)
  TREE(9,56,60,2)
  TREE(10,60,62,1)
  #undef TREE
}

// ---------------- K2: fused span attention + k-max hierarchy -----------------
#define PSTRIDE 132   // parts entry: [0..64) fa, [64] M, [65] S, [66..130) kmax (l9 only)

template<int L>
__device__ __forceinline__ void span_level(
    int tid, int bhh, int seg, unsigned gbase,
    const float* kreg, const u16* __restrict__ sq, const u16* __restrict__ vb,
    u16* __restrict__ spanv, float* e_sh, float* csum, float* wred, float* pvw)
{
  const int j = tid;
  const int wv = tid >> 6;
  unsigned srow = LO[L-1] + (unsigned)bhh*(2048u>>L)
                + (unsigned)(seg*(256>>L)) + (unsigned)(j>>L);
  float d = dotrow(kreg, sq + (size_t)srow*64u);

  float M = d;
  if constexpr (L<=6) {
    #pragma unroll
    for (int o=1;o<(1<<L);o<<=1) M = fmaxf(M, __shfl_xor(M,o));
  } else {
    #pragma unroll
    for (int o=1;o<64;o<<=1) M = fmaxf(M, __shfl_xor(M,o));
    if ((tid&63)==0) wred[wv] = M;
    __syncthreads();
    if constexpr (L==7) M = fmaxf(wred[wv&2], wred[(wv&2)|1]);
    else M = fmaxf(fmaxf(wred[0],wred[1]),fmaxf(wred[2],wred[3]));
    __syncthreads();
  }
  float e = __expf(d - M);
  e_sh[j] = e;
  float S = e;
  if constexpr (L<=6) {
    #pragma unroll
    for (int o=1;o<(1<<L);o<<=1) S += __shfl_xor(S,o);
  } else {
    #pragma unroll
    for (int o=1;o<64;o<<=1) S += __shfl_xor(S,o);
    if ((tid&63)==0) wred[wv] = S;
    __syncthreads();
    if constexpr (L==7) S = wred[wv&2] + wred[(wv&2)|1];
    else S = wred[0]+wred[1]+wred[2]+wred[3];
    __syncthreads();
  }
  if constexpr (L<=2) { if ((j&((1<<L)-1))==0) csum[j>>L] = S; }
  __syncthreads();

  if constexpr (L<=2) {
    #pragma unroll
    for (int p0=0; p0<(256>>L)*8; p0+=256){
      int p = p0 + tid;
      int c = p>>3, oct = p&7;
      float fa[8] = {0,0,0,0,0,0,0,0};
      #pragma unroll
      for (int jj=0;jj<(1<<L);jj++){
        int row = (c<<L)|jj;
        fma8(fa, e_sh[row], *(const uint4*)(vb + gbase + (unsigned)row*1024u + oct*8));
      }
      float inv = 1.f/csum[c];
      #pragma unroll
      for (int i=0;i<8;i++) fa[i] *= inv;
      unsigned grow = LO[L-1] + (unsigned)bhh*(2048u>>L) + (unsigned)(seg*(256>>L)) + c;
      *(uint4*)(spanv + grow*64u + oct*8u) = pk8(fa);
    }
  } else {
    int u = tid & ((1<<L)-1);
    int c = tid >> L;
    int oct = u & 7;
    int r0 = (u>>3)*8;
    float fa[8] = {0,0,0,0,0,0,0,0};
    #pragma unroll
    for (int jj=0;jj<8;jj++){
      int row = (c<<L) + r0 + jj;
      fma8(fa, e_sh[row], *(const uint4*)(vb + gbase + (unsigned)row*1024u + oct*8));
    }
    #pragma unroll
    for (int o=8; o<(1<<(L<=6?L:6)); o<<=1)
      #pragma unroll
      for (int i=0;i<8;i++) fa[i] += __shfl_xor(fa[i],o);
    if constexpr (L>=7){
      if ((tid&63)<8)
        #pragma unroll
        for (int i=0;i<8;i++) pvw[(wv*8+oct)*8+i] = fa[i];
      __syncthreads();
      if constexpr (L==7){
        if ((tid&127)<8)
          #pragma unroll
          for (int i=0;i<8;i++) fa[i] += pvw[(((wv)|1)*8+oct)*8+i];
      } else {
        if (tid<8)
          #pragma unroll
          for (int i=0;i<8;i++) fa[i] += pvw[(1*8+oct)*8+i]+pvw[(2*8+oct)*8+i]+pvw[(3*8+oct)*8+i];
      }
    }
    bool writer = (L<7) ? (u<8) : ((L==7) ? ((tid&127)<8) : (tid<8));
    if (writer){
      float inv = 1.f/S;
      #pragma unroll
      for (int i=0;i<8;i++) fa[i] *= inv;
      unsigned grow = LO[L-1] + (unsigned)bhh*(2048u>>L) + (unsigned)(seg*(256>>L)) + c;
      *(uint4*)(spanv + grow*64u + oct*8u) = pk8(fa);
    }
  }
  __syncthreads();
}

__device__ __forceinline__ void partial_level(
    int tid, float d, unsigned gbase, const u16* __restrict__ vb,
    float* e_sh, float* wred, float* pvw, float* __restrict__ entry)
{
  const int wv = tid >> 6;
  float M = d;
  #pragma unroll
  for (int o=1;o<64;o<<=1) M = fmaxf(M, __shfl_xor(M,o));
  if ((tid&63)==0) wred[wv] = M;
  __syncthreads();
  M = fmaxf(fmaxf(wred[0],wred[1]), fmaxf(wred[2],wred[3]));
  __syncthreads();
  float e = __expf(d - M);
  e_sh[tid] = e;
  float S = e;
  #pragma unroll
  for (int o=1;o<64;o<<=1) S += __shfl_xor(S,o);
  if ((tid&63)==0) wred[wv] = S;
  __syncthreads();
  S = wred[0]+wred[1]+wred[2]+wred[3];

  int oct = tid&7, r0 = (tid>>3)*8;
  float fa[8] = {0,0,0,0,0,0,0,0};
  #pragma unroll
  for (int jj=0;jj<8;jj++){
    int row = r0+jj;
    fma8(fa, e_sh[row], *(const uint4*)(vb + gbase + (unsigned)row*1024u + oct*8));
  }
  #pragma unroll
  for (int o=8;o<64;o<<=1)
    #pragma unroll
    for (int i=0;i<8;i++) fa[i] += __shfl_xor(fa[i],o);
  __syncthreads();
  if ((tid&63)<8)
    #pragma unroll
    for (int i=0;i<8;i++) pvw[(wv*8+oct)*8+i] = fa[i];
  __syncthreads();
  if (tid<8){
    #pragma unroll
    for (int i=0;i<8;i++)
      fa[i] += pvw[(1*8+oct)*8+i]+pvw[(2*8+oct)*8+i]+pvw[(3*8+oct)*8+i];
    #pragma unroll
    for (int i=0;i<8;i++) entry[oct*8+i] = fa[i];
  }
  if (tid==0){ entry[64]=M; entry[65]=S; }
  __syncthreads();
}

__global__ __launch_bounds__(256) void spanv_kernel(
    const u16* __restrict__ kb, const u16* __restrict__ vb,
    const u16* __restrict__ sq, u16* __restrict__ spanv, u16* __restrict__ spank,
    float* __restrict__ parts)
{
  __shared__ __align__(16) u16 ksh[256*64];
  __shared__ float e_sh[256];
  __shared__ float csum[128];
  __shared__ float wred[4];
  __shared__ float pvw[4*8*8];
  __shared__ float wkm[4][64];
  __shared__ float wk7[2][64];

  int bid = blockIdx.x;
  int bhh = bid>>3, seg = bid&7;
  int b = bhh>>4, h = bhh&15;
  int tid = threadIdx.x, lane = tid & 63, wv = tid >> 6;
  unsigned gbase = ((unsigned)(b*2048 + seg*256))*1024u + (unsigned)h*64u;

  #pragma unroll
  for (int it=0; it<8; ++it){
    int r = it*32 + (tid>>3);
    int c = tid&7;
    uint4 v = *(const uint4*)(kb + gbase + (unsigned)r*1024u + c*8);
    *(uint4*)&ksh[(r*8 + (c^(r&7)))*8] = v;
  }
  __syncthreads();
  float kreg[64];
  #pragma unroll
  for (int c=0;c<8;c++){
    uint4 v = *(const uint4*)&ksh[(tid*8 + (c^(tid&7)))*8];
    up8(v, kreg+c*8);
  }

  span_level<1>(tid,bhh,seg,gbase,kreg,sq,vb,spanv,e_sh,csum,wred,pvw);
  span_level<2>(tid,bhh,seg,gbase,kreg,sq,vb,spanv,e_sh,csum,wred,pvw);
  span_level<3>(tid,bhh,seg,gbase,kreg,sq,vb,spanv,e_sh,csum,wred,pvw);
  span_level<4>(tid,bhh,seg,gbase,kreg,sq,vb,spanv,e_sh,csum,wred,pvw);
  span_level<5>(tid,bhh,seg,gbase,kreg,sq,vb,spanv,e_sh,csum,wred,pvw);
  span_level<6>(tid,bhh,seg,gbase,kreg,sq,vb,spanv,e_sh,csum,wred,pvw);
  span_level<7>(tid,bhh,seg,gbase,kreg,sq,vb,spanv,e_sh,csum,wred,pvw);
  span_level<8>(tid,bhh,seg,gbase,kreg,sq,vb,spanv,e_sh,csum,wred,pvw);

  float d9  = dotrow(kreg, sq + (size_t)(LO[8] + (unsigned)bhh*4u + (unsigned)(seg>>1))*64u);
  float d10 = dotrow(kreg, sq + (size_t)(LO[9] + (unsigned)bhh*2u + (unsigned)(seg>>2))*64u);
  partial_level(tid, d9,  gbase, vb, e_sh, wred, pvw, parts + (size_t)(bhh*8+seg)*PSTRIDE);
  partial_level(tid, d10, gbase, vb, e_sh, wred, pvw, parts + (size_t)(1024 + bhh*8+seg)*PSTRIDE);

  // ---- k-max hierarchy (destroys kreg): thread tid holds row tid ----
  // levels 1..6: butterfly within wave; writer u==0 of each chunk writes all 64 dims
  #pragma unroll
  for (int l=1; l<=6; ++l){
    #pragma unroll
    for (int i=0;i<64;i++) kreg[i] = fmaxf(kreg[i], __shfl_xor(kreg[i], 1<<(l-1)));
    if ((tid & ((1<<l)-1)) == 0){
      int c = tid >> l;
      unsigned grow = LO[l-1] + (unsigned)bhh*(2048u>>l) + (unsigned)(seg*(256>>l)) + c;
      #pragma unroll
      for (int j=0;j<8;j++)
        *(uint4*)(spank + grow*64u + j*8) = pk8(kreg + j*8);
    }
  }
  // wave maxes -> LDS (lane 0 writes all 64 dims, static indices)
  if (lane == 0){
    #pragma unroll
    for (int i=0;i<64;i++) wkm[wv][i] = kreg[i];
  }
  __syncthreads();
  // level 7: chunk c = waves {2c,2c+1}
  if (tid < 128){
    int c = tid>>6, d = tid&63;
    float m7 = fmaxf(wkm[2*c][d], wkm[2*c+1][d]);
    unsigned grow = LO[6] + (unsigned)bhh*16u + (unsigned)(seg*2 + c);
    spank[grow*64u + d] = f2b(m7);
    wk7[c][d] = m7;
  }
  __syncthreads();
  // level 8 (= segment max): write spank + parts l9 entry kmax
  if (tid < 64){
    float m8 = fmaxf(wk7[0][tid], wk7[1][tid]);
    unsigned grow = LO[7] + (unsigned)bhh*8u + (unsigned)seg;
    spank[grow*64u + tid] = f2b(m8);
    parts[(size_t)(bhh*8+seg)*PSTRIDE + 66 + tid] = m8;
  }
}

// ---------------- K3: combine level 9/10 partials + k-maxes ----------------
__global__ __launch_bounds__(64) void spancomb_kernel(
    const float* __restrict__ parts, u16* __restrict__ spanv, u16* __restrict__ spank)
{
  int bid = blockIdx.x, d = threadIdx.x;
  if (bid < 512){
    int bhh = bid>>2, m9 = bid&3;
    const float* p0 = parts + (size_t)(bhh*8 + m9*2)*PSTRIDE;
    const float* p1 = p0 + PSTRIDE;
    float m0=p0[64], s0=p0[65], m1=p1[64], s1=p1[65];
    float M = fmaxf(m0,m1);
    float e0 = __expf(m0-M), e1 = __expf(m1-M);
    float S = s0*e0 + s1*e1;
    float A = p0[d]*e0 + p1[d]*e1;
    unsigned grow = LO[8] + (unsigned)bhh*4u + (unsigned)m9;
    spanv[grow*64u + d] = f2b(A/S);
    float km = fmaxf(p0[66+d], p1[66+d]);
    spank[grow*64u + d] = f2b(km);
  } else {
    int cid = bid-512; int bhh = cid>>1, m10 = cid&1;
    const float* pp = parts + (size_t)(1024 + bhh*8 + m10*4)*PSTRIDE;
    float M = -1e30f;
    #pragma unroll
    for (int p=0;p<4;p++) M = fmaxf(M, pp[p*PSTRIDE+64]);
    float S=0.f, A=0.f;
    #pragma unroll
    for (int p=0;p<4;p++){
      float sc = __expf(pp[p*PSTRIDE+64]-M);
      S += pp[p*PSTRIDE+65]*sc;
      A += pp[p*PSTRIDE+d]*sc;
    }
    unsigned grow = LO[9] + (unsigned)bhh*2u + (unsigned)m10;
    spanv[grow*64u + d] = f2b(A/S);
    const float* p9 = parts + (size_t)(bhh*8 + m10*4)*PSTRIDE;
    float km = -1e30f;
    #pragma unroll
    for (int p=0;p<4;p++) km = fmaxf(km, p9[p*PSTRIDE + 66 + d]);
    spank[grow*64u + d] = f2b(km);
  }
}

// ---------------- merge: 2 threads per (b,t,h), 32 dims each ----------------
__device__ __forceinline__ float dot32(const u16* __restrict__ row, const float* __restrict__ qd){
  float s = 0.f;
  #pragma unroll
  for (int j=0;j<4;j++){
    uint4 kv = *(const uint4*)(row + j*8);
    s += qd[j*8+0]*bl(kv.x) + qd[j*8+1]*bh(kv.x);
    s += qd[j*8+2]*bl(kv.y) + qd[j*8+3]*bh(kv.y);
    s += qd[j*8+4]*bl(kv.z) + qd[j*8+5]*bh(kv.z);
    s += qd[j*8+6]*bl(kv.w) + qd[j*8+7]*bh(kv.w);
  }
  return s;
}
__device__ __forceinline__ void axpy32(float w, const u16* __restrict__ row, float* __restrict__ acc){
  #pragma unroll
  for (int j=0;j<4;j++){
    uint4 kv = *(const uint4*)(row + j*8);
    acc[j*8+0] += w*bl(kv.x); acc[j*8+1] += w*bh(kv.x);
    acc[j*8+2] += w*bl(kv.y); acc[j*8+3] += w*bh(kv.y);
    acc[j*8+4] += w*bl(kv.z); acc[j*8+5] += w*bh(kv.z);
    acc[j*8+6] += w*bl(kv.w); acc[j*8+7] += w*bh(kv.w);
  }
}

__global__ __launch_bounds__(256) void merge_kernel(
    const u16* __restrict__ q, const u16* __restrict__ k, const u16* __restrict__ v,
    const u16* __restrict__ spank, const u16* __restrict__ spanv,
    u16* __restrict__ merged)
{
  int tid  = threadIdx.x;
  int eidx = blockIdx.x*128 + (tid>>1);
  int half = tid & 1;
  int h = eidx & 15;
  int t = (eidx >> 4) & (T_-1);
  unsigned qrow = (unsigned)eidx*64u + (unsigned)half*32u;
  int b = eidx >> 15;
  int bhh = b*16 + h;

  float qd[32];
  {
    const u16* qr = q + qrow;
    #pragma unroll
    for (int j=0;j<4;j++){
      uint4 kv = *(const uint4*)(qr + j*8);
      qd[j*8+0]=bl(kv.x); qd[j*8+1]=bh(kv.x);
      qd[j*8+2]=bl(kv.y); qd[j*8+3]=bh(kv.y);
      qd[j*8+4]=bl(kv.z); qd[j*8+5]=bh(kv.z);
      qd[j*8+6]=bl(kv.w); qd[j*8+7]=bh(kv.w);
    }
  }

  float lg[12];
  unsigned off[11];
  unsigned msk = 0;
  { float p = dot32(k + qrow, qd); lg[0] = p + __shfl_xor(p, 1); }

  #pragma unroll
  for (int l=0; l<LOGL; l++){
    const int c = 1<<l;
    bool mk = false; unsigned o = 0;
    if (t >= c) {
      int m = (t - c) >> l;
      if ((m & 1) == 0) {
        mk = true;
        if (l == 0) {
          o = qrow - 1024u;
        } else {
          unsigned row = LO[l-1] + (unsigned)bhh*(2048u>>l) + (unsigned)m;
          o = row*64u + (unsigned)half*32u;
        }
      }
    }
    float L = -1e30f;
    if (mk) {
      const u16* row = (l==0) ? (k + o) : (spank + o);
      float p = dot32(row, qd);
      L = p + __shfl_xor(p, 1);
    }
    lg[l+1] = L;
    off[l] = o;
    if (mk) msk |= (1u<<l);
  }

  float M = lg[0];
  #pragma unroll
  for (int i=1;i<12;i++) M = fmaxf(M, lg[i]);
  float w[12]; float s = 0.f;
  #pragma unroll
  for (int i=0;i<12;i++){ w[i] = __expf(lg[i]-M); s += w[i]; }

  float acc[32];
  #pragma unroll
  for (int d=0;d<32;d++) acc[d] = 0.f;
  axpy32(w[0], v + qrow, acc);
  #pragma unroll
  for (int l=0; l<LOGL; l++){
    if (msk & (1u<<l)) {
      const u16* row = (l==0) ? (v + off[l]) : (spanv + off[l]);
      axpy32(w[l+1], row, acc);
    }
  }

  float inv = 1.f/s;
  u16 ob[32];
  #pragma unroll
  for (int d=0;d<32;d++) ob[d] = f2b(acc[d]*inv);
  u16* orow = merged + qrow;
  *(uint4*)(orow)      = *(uint4*)(ob);
  *(uint4*)(orow + 8)  = *(uint4*)(ob+8);
  *(uint4*)(orow + 16) = *(uint4*)(ob+16);
  *(uint4*)(orow + 24) = *(uint4*)(ob+24);
}

// ---------------- launch ----------------
extern "C" void kernel_launch(void* const* d_in, const int* in_sizes, int n_in,
                              void* d_out, int out_size, void* d_ws, size_t ws_size,
                              hipStream_t stream) {
  (void)in_sizes; (void)n_in; (void)out_size; (void)ws_size;
  const float* x  = (const float*)d_in[0];
  const float* Wq = (const float*)d_in[1];
  const float* Wk = (const float*)d_in[2];
  const float* Wv = (const float*)d_in[3];
  const float* Wo = (const float*)d_in[4];
  float* out = (float*)d_out;

  uint8_t* w = (uint8_t*)d_ws;
  u16* xb     = (u16*)(w);                   // 32 MB (reused as merged)
  u16* qb     = (u16*)(w + 33554432ull);     // 32 MB
  u16* kb     = (u16*)(w + 67108864ull);     // 32 MB
  u16* vb     = (u16*)(w + 100663296ull);    // 32 MB
  u16* spank  = (u16*)(w + 134217728ull);    // 32 MB
  u16* spanv  = (u16*)(w + 167772160ull);    // 32 MB
  u16* wqkvT  = (u16*)(w + 201326592ull);    // 6 MB
  u16* woT    = (u16*)(w + 207618048ull);    // 2 MB
  // scratch in d_out (dead until final gemm overwrites it):
  u16*   sqArr = (u16*)d_out;                             // 33.5 MB
  float* parts = (float*)((uint8_t*)d_out + 50331648ull); // ~1.1 MB @ +48MB

  convert_x_kernel<<<8192, 256, 0, stream>>>(x, xb);
  wtrans_kernel<<<dim3(16,16,4), 256, 0, stream>>>(Wq, Wk, Wv, Wo, wqkvT, woT);

  gemm256_kernel<1><<<768, 512, 0, stream>>>(xb, wqkvT, nullptr, qb, kb, vb,
                                             16384, 3072, 1024, 12);

  spanmax_kernel<<<256, 256, 0, stream>>>(qb, sqArr);
  spanv_kernel<<<1024, 256, 0, stream>>>(kb, vb, sqArr, spanv, spank, parts);
  spancomb_kernel<<<768, 64, 0, stream>>>(parts, spanv, spank);

  merge_kernel<<<2048, 256, 0, stream>>>(qb, kb, vb, spank, spanv, xb /*merged*/);

  gemm256_kernel<0><<<256, 512, 0, stream>>>(xb, woT, out, nullptr, nullptr, nullptr,
                                             16384, 1024, 1024, 4);
}

// Round 13
// 305.711 us; speedup vs baseline: 1.0691x; 1.0691x over previous
//
#include <hip/hip_runtime.h>
#include <hip/hip_bf16.h>
#include <stdint.h>

// SelfAttLogn: B=8 T=2048 DM=1024 H=16 DH=64, LOG_LEN=11
// convert x | transpose W | QKV gemm (256^2 burst-staged, ANTI-PHASE K-half waves)
// | spanmax | spanv | spancomb | merge | out gemm   (tail = round-8 proven versions)

typedef unsigned short u16;
typedef __attribute__((ext_vector_type(8))) short bf16x8;
typedef __attribute__((ext_vector_type(4))) float f32x4;

#define B_ 8
#define T_ 2048
#define H_ 16
#define DHD 64
#define LOGL 11

// span row offsets per level (rows of 64 elems), head-major: row = LO[l-1] + bh*n_l + m
__device__ constexpr unsigned LO[10] = {0u,131072u,196608u,229376u,245760u,
                                        253952u,258048u,260096u,261120u,261632u};

__device__ __forceinline__ float b2f(u16 u){
  union { float f; unsigned int i; } x; x.i = ((unsigned int)u) << 16; return x.f;
}
__device__ __forceinline__ float bl(unsigned u){
  union { float f; unsigned int i; } x; x.i = u << 16; return x.f;
}
__device__ __forceinline__ float bh(unsigned u){
  union { float f; unsigned int i; } x; x.i = u & 0xffff0000u; return x.f;
}
__device__ __forceinline__ u16 f2b(float f){
  union { float f; unsigned int i; } x; x.f = f;
  unsigned int r = x.i + 0x7fffu + ((x.i >> 16) & 1u);
  return (u16)(r >> 16);
}
__device__ __forceinline__ void up8(uint4 v, float* f){
  f[0]=bl(v.x); f[1]=bh(v.x); f[2]=bl(v.y); f[3]=bh(v.y);
  f[4]=bl(v.z); f[5]=bh(v.z); f[6]=bl(v.w); f[7]=bh(v.w);
}
__device__ __forceinline__ uint4 pk8(const float* f){
  uint4 o; u16* p=(u16*)&o;
  #pragma unroll
  for (int i=0;i<8;i++) p[i]=f2b(f[i]);
  return o;
}
__device__ __forceinline__ void cp8(float* a, const float* b){
  #pragma unroll
  for (int i=0;i<8;i++) a[i]=b[i];
}
__device__ __forceinline__ void mx8(float* a, const float* b){
  #pragma unroll
  for (int i=0;i<8;i++) a[i]=fmaxf(a[i],b[i]);
}
__device__ __forceinline__ void fma8(float* fa, float w, uint4 v){
  fa[0]+=w*bl(v.x); fa[1]+=w*bh(v.x); fa[2]+=w*bl(v.y); fa[3]+=w*bh(v.y);
  fa[4]+=w*bl(v.z); fa[5]+=w*bh(v.z); fa[6]+=w*bl(v.w); fa[7]+=w*bh(v.w);
}
__device__ __forceinline__ float dotrow(const float* kreg, const u16* sp){
  float d = 0.f;
  #pragma unroll
  for (int c=0;c<8;c++){
    uint4 t4 = *(const uint4*)(sp + c*8);
    d += kreg[c*8+0]*bl(t4.x) + kreg[c*8+1]*bh(t4.x)
       + kreg[c*8+2]*bl(t4.y) + kreg[c*8+3]*bh(t4.y)
       + kreg[c*8+4]*bl(t4.z) + kreg[c*8+5]*bh(t4.z)
       + kreg[c*8+6]*bl(t4.w) + kreg[c*8+7]*bh(t4.w);
  }
  return d;
}
__device__ __forceinline__ void gload_lds16(const void* g, void* l) {
  __builtin_amdgcn_global_load_lds((const __attribute__((address_space(1))) void*)g,
                                   (__attribute__((address_space(3))) void*)l, 16, 0, 0);
}

#define BARRIER() __builtin_amdgcn_s_barrier()
#define VMW(N) asm volatile("s_waitcnt vmcnt(" #N ")" ::: "memory")

// ---------------- convert x to bf16 ----------------
__global__ __launch_bounds__(256) void convert_x_kernel(
    const float* __restrict__ x, u16* __restrict__ xb)
{
  size_t i = ((size_t)blockIdx.x*256 + threadIdx.x)*8;
  float4 a = *(const float4*)(x+i);
  float4 b = *(const float4*)(x+i+4);
  u16 o[8] = {f2b(a.x),f2b(a.y),f2b(a.z),f2b(a.w),f2b(b.x),f2b(b.y),f2b(b.z),f2b(b.w)};
  *(uint4*)(xb+i) = *(uint4*)o;
}

// ---------------- transpose-convert weights ----------------
__global__ __launch_bounds__(256) void wtrans_kernel(
    const float* __restrict__ w0, const float* __restrict__ w1,
    const float* __restrict__ w2, const float* __restrict__ w3,
    u16* __restrict__ wqkvT, u16* __restrict__ woT)
{
  __shared__ u16 tile[64][65];
  int mat = blockIdx.z;
  const float* src = (mat==0)?w0:(mat==1)?w1:(mat==2)?w2:w3;
  u16* dst = (mat<3) ? (wqkvT + (size_t)mat*1048576ull) : woT;
  int r0 = blockIdx.y*64, c0 = blockIdx.x*64;
  int t = threadIdx.x;
  int tr = t>>4, tc = (t&15)*4;
  #pragma unroll
  for (int i=0;i<4;i++){
    int r = tr + i*16;
    float4 a = *(const float4*)(src + (size_t)(r0+r)*1024 + c0 + tc);
    tile[tc+0][r] = f2b(a.x);
    tile[tc+1][r] = f2b(a.y);
    tile[tc+2][r] = f2b(a.z);
    tile[tc+3][r] = f2b(a.w);
  }
  __syncthreads();
  #pragma unroll
  for (int i=0;i<4;i++){
    int rr = tr + i*16;
    uint2 o; u16* p = (u16*)&o;
    p[0]=tile[rr][tc+0]; p[1]=tile[rr][tc+1]; p[2]=tile[rr][tc+2]; p[3]=tile[rr][tc+3];
    *(uint2*)(dst + (size_t)(c0+rr)*1024 + r0 + tc) = o;
  }
}

// ---------------- 256^2 bf16 GEMM: burst-staged, anti-phase K-half waves --------
// 512 thr, 8 waves (2Mx4N), wave output 128x64 (acc[8][4]), BK=64 = 2 K-halves.
// Whole next tile burst-staged at tile start; wr=0 waves compute kk 0->1 while
// wr=1 waves compute kk 1->0 -> each SIMD has one reading + one MFMAing wave.
#define HALF(KK)                                                            \
  do {                                                                      \
    _Pragma("unroll") for (int mi=0;mi<8;++mi) afr[mi] = ldsA(buf, mi, KK); \
    _Pragma("unroll") for (int nj=0;nj<4;++nj) bfr[nj] = ldsB(buf, nj, KK); \
    __builtin_amdgcn_s_setprio(1);                                          \
    _Pragma("unroll") for (int mi=0;mi<8;++mi)                              \
    _Pragma("unroll") for (int nj=0;nj<4;++nj)                              \
      acc[mi][nj] = __builtin_amdgcn_mfma_f32_16x16x32_bf16(                \
          afr[mi], bfr[nj], acc[mi][nj], 0, 0, 0);                          \
    __builtin_amdgcn_s_setprio(0);                                          \
  } while(0)

template<int MODE>
__global__ __launch_bounds__(512, 2) void gemm256_kernel(
    const u16* __restrict__ A, const u16* __restrict__ BT,
    float* __restrict__ C,
    u16* __restrict__ Qp, u16* __restrict__ Kp, u16* __restrict__ Vp,
    int M, int N, int K, int nxtile)
{
  __shared__ __align__(16) u16 As[2][16384];   // [buf][row*64 + chunk*8], rows 0..255
  __shared__ __align__(16) u16 Bs[2][16384];

  int cpx = gridDim.x >> 3;
  int wg  = blockIdx.x;
  int swz = (wg & 7)*cpx + (wg >> 3);
  const int bx = swz % nxtile, by = swz / nxtile;
  const int m0 = by*256, n0 = bx*256;
  const int tid = threadIdx.x;
  const int lane = tid & 63, w = tid >> 6;
  const int wr = w >> 2, wc = w & 3;

  f32x4 acc[8][4];
  #pragma unroll
  for (int i=0;i<8;i++)
    #pragma unroll
    for (int j=0;j<4;j++) acc[i][j] = (f32x4)0.f;

  // burst-stage a whole K-tile (A 256x64 + B 256x64): 8 gload_lds/thread.
  // LDS dest linear; global source col inverse-XOR-swizzled (T2 both-sides).
  const int rr   = tid >> 3;
  const int colb = ((tid & 7)*16) ^ ((rr & 7) << 4);   // (q*64+rr)&7 == rr&7
  const u16* gA = A  + (size_t)(m0 + rr)*K + (colb >> 1);
  const u16* gB = BT + (size_t)(n0 + rr)*K + (colb >> 1);

  auto stageTile = [&](int t){
    const int sbuf = t & 1;
    const int kb  = t*64;
    #pragma unroll
    for (int q=0; q<4; ++q)
      gload_lds16(gA + (size_t)(q*64)*K + kb, &As[sbuf][q*64*64] + tid*8);
    #pragma unroll
    for (int q=0; q<4; ++q)
      gload_lds16(gB + (size_t)(q*64)*K + kb, &Bs[sbuf][q*64*64] + tid*8);
  };
  auto ldsA = [&](int buf, int mi, int kk)->bf16x8 {
    int r = wr*128 + mi*16 + (lane&15);
    int chunk = (kk*4 + (lane>>4)) ^ (r&7);
    return *(const bf16x8*)&As[buf][r*64 + chunk*8];
  };
  auto ldsB = [&](int buf, int nj, int kk)->bf16x8 {
    int r = wc*64 + nj*16 + (lane&15);
    int chunk = (kk*4 + (lane>>4)) ^ (r&7);
    return *(const bf16x8*)&Bs[buf][r*64 + chunk*8];
  };

  bf16x8 afr[8], bfr[4];
  const int NT = K >> 6;                      // 16 for K=1024

  stageTile(0);
  VMW(0);
  BARRIER();

  // anti-phase: wr=0 waves kk 0->1, wr=1 waves kk 1->0 (wave-uniform branch;
  // waves w and w+4 share a SIMD and have opposite wr -> pipes overlap)
  for (int t = 0; t < NT; ++t) {
    const int buf = t & 1;
    if (t+1 < NT) stageTile(t+1);
    if (wr) { HALF(1); HALF(0); }
    else    { HALF(0); HALF(1); }
    VMW(0);
    BARRIER();
  }

  // epilogue: C/D layout col=lane&15, row=(lane>>4)*4+reg  [m89-verified]
  if (MODE == 0) {
    #pragma unroll
    for (int mi=0; mi<8; mi++)
      #pragma unroll
      for (int nj=0; nj<4; nj++){
        int row = m0 + wr*128 + mi*16 + ((lane>>4)<<2);
        int col = n0 + wc*64 + nj*16 + (lane&15);
        #pragma unroll
        for (int r=0;r<4;r++)
          C[(size_t)(row+r)*N + col] = acc[mi][nj][r];
      }
  } else {
    int mat = n0 >> 10;
    u16* dst = (mat==0) ? Qp : (mat==1 ? Kp : Vp);
    float sc = (mat==0) ? 0.125f : 1.0f;
    int cc0 = n0 & 1023;
    #pragma unroll
    for (int mi=0; mi<8; mi++)
      #pragma unroll
      for (int nj=0; nj<4; nj++){
        int row = m0 + wr*128 + mi*16 + ((lane>>4)<<2);
        int col = cc0 + wc*64 + nj*16 + (lane&15);
        #pragma unroll
        for (int r=0;r<4;r++)
          dst[(size_t)(row+r)*1024 + col] = f2b(acc[mi][nj][r]*sc);
      }
  }
}

// ---------------- K1: all-level max hierarchy (sq from q, spank from k) ----------
__global__ __launch_bounds__(256) void spanmax_kernel(
    const u16* __restrict__ qb, const u16* __restrict__ kb,
    u16* __restrict__ sqArr, u16* __restrict__ spank)
{
  __shared__ __align__(16) u16 lsh[63*64];
  int bid = blockIdx.x;
  int tensor = bid >> 8;
  int idx = bid & 255;
  int bhh = idx >> 1, half = idx & 1;
  int b = bhh >> 4, h = bhh & 15;
  const u16* src = tensor ? kb : qb;
  u16* dst = tensor ? spank : sqArr;
  int tid = threadIdx.x;
  int m5 = tid >> 3, oct = tid & 7;
  int tbase = half*1024 + m5*32;
  unsigned gbase = ((unsigned)(b*2048 + tbase))*1024u + (unsigned)h*64u + (unsigned)oct*8u;

  float c1[8],c2[8],c3[8],c4[8],c5[8],f[8];
  #pragma unroll
  for (int jj=0;jj<32;jj++){
    uint4 v = *(const uint4*)(src + gbase + (unsigned)jj*1024u);
    up8(v,f);
    if ((jj&1)==0) { cp8(c1,f); }
    else {
      mx8(c1,f);
      { unsigned grow = LO[0] + (unsigned)bhh*1024u + (unsigned)((tbase+jj)>>1);
        *(uint4*)(dst + grow*64u + oct*8u) = pk8(c1); }
      if ((jj&3)==1) cp8(c2,c1); else mx8(c2,c1);
      if ((jj&3)==3){
        unsigned grow = LO[1] + (unsigned)bhh*512u + (unsigned)((tbase+jj)>>2);
        *(uint4*)(dst + grow*64u + oct*8u) = pk8(c2);
        if ((jj&7)==3) cp8(c3,c2); else mx8(c3,c2);
        if ((jj&7)==7){
          unsigned g3 = LO[2] + (unsigned)bhh*256u + (unsigned)((tbase+jj)>>3);
          *(uint4*)(dst + g3*64u + oct*8u) = pk8(c3);
          if ((jj&15)==7) cp8(c4,c3); else mx8(c4,c3);
          if ((jj&15)==15){
            unsigned g4 = LO[3] + (unsigned)bhh*128u + (unsigned)((tbase+jj)>>4);
            *(uint4*)(dst + g4*64u + oct*8u) = pk8(c4);
            if (jj==15) cp8(c5,c4); else mx8(c5,c4);
            if (jj==31){
              unsigned g5 = LO[4] + (unsigned)bhh*64u + (unsigned)((tbase+jj)>>5);
              uint4 pk = pk8(c5);
              *(uint4*)(dst + g5*64u + oct*8u) = pk;
              *(uint4*)&lsh[(m5*8+oct)*8] = pk;
            }
          }
        }
      }
    }
  }
  __syncthreads();
  int g = tid>>3;
  #define TREE(LV, INOFF, OUTOFF, NR)                                        \
    if (g < (NR)) {                                                          \
      float a[8], bb[8];                                                     \
      up8(*(const uint4*)&lsh[(((INOFF)+2*g)*8+oct)*8], a);                  \
      up8(*(const uint4*)&lsh[(((INOFF)+2*g+1)*8+oct)*8], bb);               \
      mx8(a,bb);                                                             \
      uint4 pk = pk8(a);                                                     \
      unsigned grow = LO[LV-1] + (unsigned)bhh*(2048u>>LV)                   \
                    + (unsigned)(half*(1024>>LV)) + (unsigned)g;             \
      *(uint4*)(dst + grow*64u + oct*8u) = pk;                               \
      if ((LV)<10) *(uint4*)&lsh[(((OUTOFF)+g)*8+oct)*8] = pk;               \
    }                                                                        \
    __syncthreads();
  TREE(6,0,32,16)
  TREE(7,32,48,8)
  TREE(8,48,56,4)
  TREE(9,56,60,2)
  TREE(10,60,62,1)
  #undef TREE
}

// ---------------- K2: fused span attention, levels 1-8 + partials 9/10 -----------
template<int L>
__device__ __forceinline__ void span_level(
    int tid, int bhh, int seg, unsigned gbase,
    const float* kreg, const u16* __restrict__ sq, const u16* __restrict__ vb,
    u16* __restrict__ spanv, float* e_sh, float* csum, float* wred, float* pvw)
{
  const int j = tid;
  const int wv = tid >> 6;
  unsigned srow = LO[L-1] + (unsigned)bhh*(2048u>>L)
                + (unsigned)(seg*(256>>L)) + (unsigned)(j>>L);
  float d = dotrow(kreg, sq + (size_t)srow*64u);

  float M = d;
  if constexpr (L<=6) {
    #pragma unroll
    for (int o=1;o<(1<<L);o<<=1) M = fmaxf(M, __shfl_xor(M,o));
  } else {
    #pragma unroll
    for (int o=1;o<64;o<<=1) M = fmaxf(M, __shfl_xor(M,o));
    if ((tid&63)==0) wred[wv] = M;
    __syncthreads();
    if constexpr (L==7) M = fmaxf(wred[wv&2], wred[(wv&2)|1]);
    else M = fmaxf(fmaxf(wred[0],wred[1]),fmaxf(wred[2],wred[3]));
    __syncthreads();
  }
  float e = __expf(d - M);
  e_sh[j] = e;
  float S = e;
  if constexpr (L<=6) {
    #pragma unroll
    for (int o=1;o<(1<<L);o<<=1) S += __shfl_xor(S,o);
  } else {
    #pragma unroll
    for (int o=1;o<64;o<<=1) S += __shfl_xor(S,o);
    if ((tid&63)==0) wred[wv] = S;
    __syncthreads();
    if constexpr (L==7) S = wred[wv&2] + wred[(wv&2)|1];
    else S = wred[0]+wred[1]+wred[2]+wred[3];
    __syncthreads();
  }
  if constexpr (L<=2) { if ((j&((1<<L)-1))==0) csum[j>>L] = S; }
  __syncthreads();

  if constexpr (L<=2) {
    #pragma unroll
    for (int p0=0; p0<(256>>L)*8; p0+=256){
      int p = p0 + tid;
      int c = p>>3, oct = p&7;
      float fa[8] = {0,0,0,0,0,0,0,0};
      #pragma unroll
      for (int jj=0;jj<(1<<L);jj++){
        int row = (c<<L)|jj;
        fma8(fa, e_sh[row], *(const uint4*)(vb + gbase + (unsigned)row*1024u + oct*8));
      }
      float inv = 1.f/csum[c];
      #pragma unroll
      for (int i=0;i<8;i++) fa[i] *= inv;
      unsigned grow = LO[L-1] + (unsigned)bhh*(2048u>>L) + (unsigned)(seg*(256>>L)) + c;
      *(uint4*)(spanv + grow*64u + oct*8u) = pk8(fa);
    }
  } else {
    int u = tid & ((1<<L)-1);
    int c = tid >> L;
    int oct = u & 7;
    int r0 = (u>>3)*8;
    float fa[8] = {0,0,0,0,0,0,0,0};
    #pragma unroll
    for (int jj=0;jj<8;jj++){
      int row = (c<<L) + r0 + jj;
      fma8(fa, e_sh[row], *(const uint4*)(vb + gbase + (unsigned)row*1024u + oct*8));
    }
    #pragma unroll
    for (int o=8; o<(1<<(L<=6?L:6)); o<<=1)
      #pragma unroll
      for (int i=0;i<8;i++) fa[i] += __shfl_xor(fa[i],o);
    if constexpr (L>=7){
      if ((tid&63)<8)
        #pragma unroll
        for (int i=0;i<8;i++) pvw[(wv*8+oct)*8+i] = fa[i];
      __syncthreads();
      if constexpr (L==7){
        if ((tid&127)<8)
          #pragma unroll
          for (int i=0;i<8;i++) fa[i] += pvw[(((wv)|1)*8+oct)*8+i];
      } else {
        if (tid<8)
          #pragma unroll
          for (int i=0;i<8;i++) fa[i] += pvw[(1*8+oct)*8+i]+pvw[(2*8+oct)*8+i]+pvw[(3*8+oct)*8+i];
      }
    }
    bool writer = (L<7) ? (u<8) : ((L==7) ? ((tid&127)<8) : (tid<8));
    if (writer){
      float inv = 1.f/S;
      #pragma unroll
      for (int i=0;i<8;i++) fa[i] *= inv;
      unsigned grow = LO[L-1] + (unsigned)bhh*(2048u>>L) + (unsigned)(seg*(256>>L)) + c;
      *(uint4*)(spanv + grow*64u + oct*8u) = pk8(fa);
    }
  }
  __syncthreads();
}

__device__ __forceinline__ void partial_level(
    int tid, float d, unsigned gbase, const u16* __restrict__ vb,
    float* e_sh, float* wred, float* pvw, float* __restrict__ entry)
{
  const int wv = tid >> 6;
  float M = d;
  #pragma unroll
  for (int o=1;o<64;o<<=1) M = fmaxf(M, __shfl_xor(M,o));
  if ((tid&63)==0) wred[wv] = M;
  __syncthreads();
  M = fmaxf(fmaxf(wred[0],wred[1]), fmaxf(wred[2],wred[3]));
  __syncthreads();
  float e = __expf(d - M);
  e_sh[tid] = e;
  float S = e;
  #pragma unroll
  for (int o=1;o<64;o<<=1) S += __shfl_xor(S,o);
  if ((tid&63)==0) wred[wv] = S;
  __syncthreads();
  S = wred[0]+wred[1]+wred[2]+wred[3];

  int oct = tid&7, r0 = (tid>>3)*8;
  float fa[8] = {0,0,0,0,0,0,0,0};
  #pragma unroll
  for (int jj=0;jj<8;jj++){
    int row = r0+jj;
    fma8(fa, e_sh[row], *(const uint4*)(vb + gbase + (unsigned)row*1024u + oct*8));
  }
  #pragma unroll
  for (int o=8;o<64;o<<=1)
    #pragma unroll
    for (int i=0;i<8;i++) fa[i] += __shfl_xor(fa[i],o);
  __syncthreads();
  if ((tid&63)<8)
    #pragma unroll
    for (int i=0;i<8;i++) pvw[(wv*8+oct)*8+i] = fa[i];
  __syncthreads();
  if (tid<8){
    #pragma unroll
    for (int i=0;i<8;i++)
      fa[i] += pvw[(1*8+oct)*8+i]+pvw[(2*8+oct)*8+i]+pvw[(3*8+oct)*8+i];
    #pragma unroll
    for (int i=0;i<8;i++) entry[oct*8+i] = fa[i];
  }
  if (tid==0){ entry[64]=M; entry[65]=S; }
  __syncthreads();
}

__global__ __launch_bounds__(256) void spanv_kernel(
    const u16* __restrict__ kb, const u16* __restrict__ vb,
    const u16* __restrict__ sq, u16* __restrict__ spanv,
    float* __restrict__ parts)
{
  __shared__ __align__(16) u16 ksh[256*64];
  __shared__ float e_sh[256];
  __shared__ float csum[128];
  __shared__ float wred[4];
  __shared__ float pvw[4*8*8];

  int bid = blockIdx.x;
  int bhh = bid>>3, seg = bid&7;
  int b = bhh>>4, h = bhh&15;
  int tid = threadIdx.x;
  unsigned gbase = ((unsigned)(b*2048 + seg*256))*1024u + (unsigned)h*64u;

  #pragma unroll
  for (int it=0; it<8; ++it){
    int r = it*32 + (tid>>3);
    int c = tid&7;
    uint4 v = *(const uint4*)(kb + gbase + (unsigned)r*1024u + c*8);
    *(uint4*)&ksh[(r*8 + (c^(r&7)))*8] = v;
  }
  __syncthreads();
  float kreg[64];
  #pragma unroll
  for (int c=0;c<8;c++){
    uint4 v = *(const uint4*)&ksh[(tid*8 + (c^(tid&7)))*8];
    up8(v, kreg+c*8);
  }

  span_level<1>(tid,bhh,seg,gbase,kreg,sq,vb,spanv,e_sh,csum,wred,pvw);
  span_level<2>(tid,bhh,seg,gbase,kreg,sq,vb,spanv,e_sh,csum,wred,pvw);
  span_level<3>(tid,bhh,seg,gbase,kreg,sq,vb,spanv,e_sh,csum,wred,pvw);
  span_level<4>(tid,bhh,seg,gbase,kreg,sq,vb,spanv,e_sh,csum,wred,pvw);
  span_level<5>(tid,bhh,seg,gbase,kreg,sq,vb,spanv,e_sh,csum,wred,pvw);
  span_level<6>(tid,bhh,seg,gbase,kreg,sq,vb,spanv,e_sh,csum,wred,pvw);
  span_level<7>(tid,bhh,seg,gbase,kreg,sq,vb,spanv,e_sh,csum,wred,pvw);
  span_level<8>(tid,bhh,seg,gbase,kreg,sq,vb,spanv,e_sh,csum,wred,pvw);

  float d9  = dotrow(kreg, sq + (size_t)(LO[8] + (unsigned)bhh*4u + (unsigned)(seg>>1))*64u);
  float d10 = dotrow(kreg, sq + (size_t)(LO[9] + (unsigned)bhh*2u + (unsigned)(seg>>2))*64u);
  partial_level(tid, d9,  gbase, vb, e_sh, wred, pvw, parts + (size_t)(bhh*8+seg)*68u);
  partial_level(tid, d10, gbase, vb, e_sh, wred, pvw, parts + (size_t)(1024 + bhh*8+seg)*68u);
}

// ---------------- K3: combine level 9/10 partials ----------------
__global__ __launch_bounds__(64) void spancomb_kernel(
    const float* __restrict__ parts, u16* __restrict__ spanv)
{
  int bid = blockIdx.x, d = threadIdx.x;
  if (bid < 512){
    int bhh = bid>>2, m9 = bid&3;
    const float* p0 = parts + (size_t)(bhh*8 + m9*2)*68u;
    const float* p1 = p0 + 68;
    float m0=p0[64], s0=p0[65], m1=p1[64], s1=p1[65];
    float M = fmaxf(m0,m1);
    float e0 = __expf(m0-M), e1 = __expf(m1-M);
    float S = s0*e0 + s1*e1;
    float A = p0[d]*e0 + p1[d]*e1;
    unsigned grow = LO[8] + (unsigned)bhh*4u + (unsigned)m9;
    spanv[grow*64u + d] = f2b(A/S);
  } else {
    int cid = bid-512; int bhh = cid>>1, m10 = cid&1;
    const float* pp = parts + (size_t)(1024 + bhh*8 + m10*4)*68u;
    float M = -1e30f;
    #pragma unroll
    for (int p=0;p<4;p++) M = fmaxf(M, pp[p*68+64]);
    float S=0.f, A=0.f;
    #pragma unroll
    for (int p=0;p<4;p++){
      float sc = __expf(pp[p*68+64]-M);
      S += pp[p*68+65]*sc;
      A += pp[p*68+d]*sc;
    }
    unsigned grow = LO[9] + (unsigned)bhh*2u + (unsigned)m10;
    spanv[grow*64u + d] = f2b(A/S);
  }
}

// ---------------- merge: 2 threads per (b,t,h), 32 dims each ----------------
__device__ __forceinline__ float dot32(const u16* __restrict__ row, const float* __restrict__ qd){
  float s = 0.f;
  #pragma unroll
  for (int j=0;j<4;j++){
    uint4 kv = *(const uint4*)(row + j*8);
    s += qd[j*8+0]*bl(kv.x) + qd[j*8+1]*bh(kv.x);
    s += qd[j*8+2]*bl(kv.y) + qd[j*8+3]*bh(kv.y);
    s += qd[j*8+4]*bl(kv.z) + qd[j*8+5]*bh(kv.z);
    s += qd[j*8+6]*bl(kv.w) + qd[j*8+7]*bh(kv.w);
  }
  return s;
}
__device__ __forceinline__ void axpy32(float w, const u16* __restrict__ row, float* __restrict__ acc){
  #pragma unroll
  for (int j=0;j<4;j++){
    uint4 kv = *(const uint4*)(row + j*8);
    acc[j*8+0] += w*bl(kv.x); acc[j*8+1] += w*bh(kv.x);
    acc[j*8+2] += w*bl(kv.y); acc[j*8+3] += w*bh(kv.y);
    acc[j*8+4] += w*bl(kv.z); acc[j*8+5] += w*bh(kv.z);
    acc[j*8+6] += w*bl(kv.w); acc[j*8+7] += w*bh(kv.w);
  }
}

__global__ __launch_bounds__(256) void merge_kernel(
    const u16* __restrict__ q, const u16* __restrict__ k, const u16* __restrict__ v,
    const u16* __restrict__ spank, const u16* __restrict__ spanv,
    u16* __restrict__ merged)
{
  int tid  = threadIdx.x;
  int eidx = blockIdx.x*128 + (tid>>1);
  int half = tid & 1;
  int h = eidx & 15;
  int t = (eidx >> 4) & (T_-1);
  unsigned qrow = (unsigned)eidx*64u + (unsigned)half*32u;
  int b = eidx >> 15;
  int bhh = b*16 + h;

  float qd[32];
  {
    const u16* qr = q + qrow;
    #pragma unroll
    for (int j=0;j<4;j++){
      uint4 kv = *(const uint4*)(qr + j*8);
      qd[j*8+0]=bl(kv.x); qd[j*8+1]=bh(kv.x);
      qd[j*8+2]=bl(kv.y); qd[j*8+3]=bh(kv.y);
      qd[j*8+4]=bl(kv.z); qd[j*8+5]=bh(kv.z);
      qd[j*8+6]=bl(kv.w); qd[j*8+7]=bh(kv.w);
    }
  }

  float lg[12];
  unsigned off[11];
  unsigned msk = 0;
  { float p = dot32(k + qrow, qd); lg[0] = p + __shfl_xor(p, 1); }

  #pragma unroll
  for (int l=0; l<LOGL; l++){
    const int c = 1<<l;
    bool mk = false; unsigned o = 0;
    if (t >= c) {
      int m = (t - c) >> l;
      if ((m & 1) == 0) {
        mk = true;
        if (l == 0) {
          o = qrow - 1024u;
        } else {
          unsigned row = LO[l-1] + (unsigned)bhh*(2048u>>l) + (unsigned)m;
          o = row*64u + (unsigned)half*32u;
        }
      }
    }
    float L = -1e30f;
    if (mk) {
      const u16* row = (l==0) ? (k + o) : (spank + o);
      float p = dot32(row, qd);
      L = p + __shfl_xor(p, 1);
    }
    lg[l+1] = L;
    off[l] = o;
    if (mk) msk |= (1u<<l);
  }

  float M = lg[0];
  #pragma unroll
  for (int i=1;i<12;i++) M = fmaxf(M, lg[i]);
  float w[12]; float s = 0.f;
  #pragma unroll
  for (int i=0;i<12;i++){ w[i] = __expf(lg[i]-M); s += w[i]; }

  float acc[32];
  #pragma unroll
  for (int d=0;d<32;d++) acc[d] = 0.f;
  axpy32(w[0], v + qrow, acc);
  #pragma unroll
  for (int l=0; l<LOGL; l++){
    if (msk & (1u<<l)) {
      const u16* row = (l==0) ? (v + off[l]) : (spanv + off[l]);
      axpy32(w[l+1], row, acc);
    }
  }

  float inv = 1.f/s;
  u16 ob[32];
  #pragma unroll
  for (int d=0;d<32;d++) ob[d] = f2b(acc[d]*inv);
  u16* orow = merged + qrow;
  *(uint4*)(orow)      = *(uint4*)(ob);
  *(uint4*)(orow + 8)  = *(uint4*)(ob+8);
  *(uint4*)(orow + 16) = *(uint4*)(ob+16);
  *(uint4*)(orow + 24) = *(uint4*)(ob+24);
}

// ---------------- launch ----------------
extern "C" void kernel_launch(void* const* d_in, const int* in_sizes, int n_in,
                              void* d_out, int out_size, void* d_ws, size_t ws_size,
                              hipStream_t stream) {
  (void)in_sizes; (void)n_in; (void)out_size; (void)ws_size;
  const float* x  = (const float*)d_in[0];
  const float* Wq = (const float*)d_in[1];
  const float* Wk = (const float*)d_in[2];
  const float* Wv = (const float*)d_in[3];
  const float* Wo = (const float*)d_in[4];
  float* out = (float*)d_out;

  uint8_t* w = (uint8_t*)d_ws;
  u16* xb     = (u16*)(w);                   // 32 MB (reused as merged)
  u16* qb     = (u16*)(w + 33554432ull);     // 32 MB
  u16* kb     = (u16*)(w + 67108864ull);     // 32 MB
  u16* vb     = (u16*)(w + 100663296ull);    // 32 MB
  u16* spank  = (u16*)(w + 134217728ull);    // 32 MB
  u16* spanv  = (u16*)(w + 167772160ull);    // 32 MB
  u16* wqkvT  = (u16*)(w + 201326592ull);    // 6 MB
  u16* woT    = (u16*)(w + 207618048ull);    // 2 MB
  // scratch in d_out (dead until final gemm overwrites it):
  u16*   sqArr = (u16*)d_out;                             // 33.5 MB
  float* parts = (float*)((uint8_t*)d_out + 50331648ull); // 557 KB @ +48MB

  convert_x_kernel<<<8192, 256, 0, stream>>>(x, xb);
  wtrans_kernel<<<dim3(16,16,4), 256, 0, stream>>>(Wq, Wk, Wv, Wo, wqkvT, woT);

  gemm256_kernel<1><<<768, 512, 0, stream>>>(xb, wqkvT, nullptr, qb, kb, vb,
                                             16384, 3072, 1024, 12);

  spanmax_kernel<<<512, 256, 0, stream>>>(qb, kb, sqArr, spank);
  spanv_kernel<<<1024, 256, 0, stream>>>(kb, vb, sqArr, spanv, parts);
  spancomb_kernel<<<768, 64, 0, stream>>>(parts, spanv);

  merge_kernel<<<2048, 256, 0, stream>>>(qb, kb, vb, spank, spanv, xb /*merged*/);

  gemm256_kernel<0><<<256, 512, 0, stream>>>(xb, woT, out, nullptr, nullptr, nullptr,
                                             16384, 1024, 1024, 4);
}

// Round 14
// 300.647 us; speedup vs baseline: 1.0871x; 1.0168x over previous
//
#include <hip/hip_runtime.h>
#include <hip/hip_bf16.h>
#include <stdint.h>

// SelfAttLogn: B=8 T=2048 DM=1024 H=16 DH=64, LOG_LEN=11
// prep (convert x + transpose W, fused) | QKV gemm (256^2 8-phase raw-barrier, no setprio)
// | spanmax | spanv | spancomb | merge | out gemm

typedef unsigned short u16;
typedef __attribute__((ext_vector_type(8))) short bf16x8;
typedef __attribute__((ext_vector_type(4))) float f32x4;

#define B_ 8
#define T_ 2048
#define H_ 16
#define DHD 64
#define LOGL 11

// span row offsets per level (rows of 64 elems), head-major: row = LO[l-1] + bh*n_l + m
__device__ constexpr unsigned LO[10] = {0u,131072u,196608u,229376u,245760u,
                                        253952u,258048u,260096u,261120u,261632u};

__device__ __forceinline__ float b2f(u16 u){
  union { float f; unsigned int i; } x; x.i = ((unsigned int)u) << 16; return x.f;
}
__device__ __forceinline__ float bl(unsigned u){
  union { float f; unsigned int i; } x; x.i = u << 16; return x.f;
}
__device__ __forceinline__ float bh(unsigned u){
  union { float f; unsigned int i; } x; x.i = u & 0xffff0000u; return x.f;
}
__device__ __forceinline__ u16 f2b(float f){
  union { float f; unsigned int i; } x; x.f = f;
  unsigned int r = x.i + 0x7fffu + ((x.i >> 16) & 1u);
  return (u16)(r >> 16);
}
__device__ __forceinline__ void up8(uint4 v, float* f){
  f[0]=bl(v.x); f[1]=bh(v.x); f[2]=bl(v.y); f[3]=bh(v.y);
  f[4]=bl(v.z); f[5]=bh(v.z); f[6]=bl(v.w); f[7]=bh(v.w);
}
__device__ __forceinline__ uint4 pk8(const float* f){
  uint4 o; u16* p=(u16*)&o;
  #pragma unroll
  for (int i=0;i<8;i++) p[i]=f2b(f[i]);
  return o;
}
__device__ __forceinline__ void cp8(float* a, const float* b){
  #pragma unroll
  for (int i=0;i<8;i++) a[i]=b[i];
}
__device__ __forceinline__ void mx8(float* a, const float* b){
  #pragma unroll
  for (int i=0;i<8;i++) a[i]=fmaxf(a[i],b[i]);
}
__device__ __forceinline__ void fma8(float* fa, float w, uint4 v){
  fa[0]+=w*bl(v.x); fa[1]+=w*bh(v.x); fa[2]+=w*bl(v.y); fa[3]+=w*bh(v.y);
  fa[4]+=w*bl(v.z); fa[5]+=w*bh(v.z); fa[6]+=w*bl(v.w); fa[7]+=w*bh(v.w);
}
__device__ __forceinline__ float dotrow(const float* kreg, const u16* sp){
  float d = 0.f;
  #pragma unroll
  for (int c=0;c<8;c++){
    uint4 t4 = *(const uint4*)(sp + c*8);
    d += kreg[c*8+0]*bl(t4.x) + kreg[c*8+1]*bh(t4.x)
       + kreg[c*8+2]*bl(t4.y) + kreg[c*8+3]*bh(t4.y)
       + kreg[c*8+4]*bl(t4.z) + kreg[c*8+5]*bh(t4.z)
       + kreg[c*8+6]*bl(t4.w) + kreg[c*8+7]*bh(t4.w);
  }
  return d;
}
__device__ __forceinline__ void gload_lds16(const void* g, void* l) {
  __builtin_amdgcn_global_load_lds((const __attribute__((address_space(1))) void*)g,
                                   (__attribute__((address_space(3))) void*)l, 16, 0, 0);
}

#define BARRIER() __builtin_amdgcn_s_barrier()
#define VMW(N) asm volatile("s_waitcnt vmcnt(" #N ")" ::: "memory")

// ---------------- prep: convert x + transpose-convert W (fused) ----------------
__global__ __launch_bounds__(256) void prep_kernel(
    const float* __restrict__ x,
    const float* __restrict__ w0, const float* __restrict__ w1,
    const float* __restrict__ w2, const float* __restrict__ w3,
    u16* __restrict__ xb, u16* __restrict__ wqkvT, u16* __restrict__ woT)
{
  __shared__ u16 tile[64][65];
  int bidx = blockIdx.x;
  if (bidx < 8192) {
    size_t i = ((size_t)bidx*256 + threadIdx.x)*8;
    float4 a = *(const float4*)(x+i);
    float4 b = *(const float4*)(x+i+4);
    u16 o[8] = {f2b(a.x),f2b(a.y),f2b(a.z),f2b(a.w),f2b(b.x),f2b(b.y),f2b(b.z),f2b(b.w)};
    *(uint4*)(xb+i) = *(uint4*)o;
    return;
  }
  int p = bidx - 8192;                 // 0..1023
  int mat = p >> 8;
  int rem = p & 255;
  int r0 = (rem >> 4)*64, c0 = (rem & 15)*64;
  const float* src = (mat==0)?w0:(mat==1)?w1:(mat==2)?w2:w3;
  u16* dst = (mat<3) ? (wqkvT + (size_t)mat*1048576ull) : woT;
  int t = threadIdx.x;
  int tr = t>>4, tc = (t&15)*4;
  #pragma unroll
  for (int i=0;i<4;i++){
    int r = tr + i*16;
    float4 a = *(const float4*)(src + (size_t)(r0+r)*1024 + c0 + tc);
    tile[tc+0][r] = f2b(a.x);
    tile[tc+1][r] = f2b(a.y);
    tile[tc+2][r] = f2b(a.z);
    tile[tc+3][r] = f2b(a.w);
  }
  __syncthreads();
  #pragma unroll
  for (int i=0;i<4;i++){
    int rr = tr + i*16;
    uint2 o; u16* pp = (u16*)&o;
    pp[0]=tile[rr][tc+0]; pp[1]=tile[rr][tc+1]; pp[2]=tile[rr][tc+2]; pp[3]=tile[rr][tc+3];
    *(uint2*)(dst + (size_t)(c0+rr)*1024 + r0 + tc) = o;
  }
}

// ---------------- 256^2 8-phase bf16 GEMM (round-8 best, setprio removed) -------
#define MF16(AF, BF, MB, NB)                                                \
  _Pragma("unroll") for (int mi=0;mi<4;++mi)                                \
  _Pragma("unroll") for (int nj=0;nj<2;++nj)                                \
  _Pragma("unroll") for (int kk=0;kk<2;++kk)                                \
    acc[(MB)+mi][(NB)+nj] = __builtin_amdgcn_mfma_f32_16x16x32_bf16(        \
        AF[mi][kk], BF[nj][kk], acc[(MB)+mi][(NB)+nj], 0, 0, 0)

#define TILE_STEP(BUF, S1T,S1H, S2T,S2H, S3T,S3H, S4T,S4H, VN)              \
  do {                                                                      \
    _Pragma("unroll") for (int mi=0;mi<4;++mi)                              \
      _Pragma("unroll") for (int kk=0;kk<2;++kk)                            \
        afr[mi][kk] = ldsA(BUF, mi, kk);                                    \
    _Pragma("unroll") for (int nj=0;nj<2;++nj)                              \
      _Pragma("unroll") for (int kk=0;kk<2;++kk)                            \
        bfr0[nj][kk] = ldsB(BUF, nj, kk);                                   \
    if ((S1T) >= 0) stage((S1T), (S1H));                                    \
    BARRIER();                                                              \
    MF16(afr, bfr0, 0, 0);                                                  \
    BARRIER();                                                              \
    _Pragma("unroll") for (int nj=0;nj<2;++nj)                              \
      _Pragma("unroll") for (int kk=0;kk<2;++kk)                            \
        bfr1[nj][kk] = ldsB(BUF, nj+2, kk);                                 \
    if ((S2T) >= 0) stage((S2T), (S2H));                                    \
    BARRIER();                                                              \
    MF16(afr, bfr1, 0, 2);                                                  \
    BARRIER();                                                              \
    _Pragma("unroll") for (int mi=0;mi<4;++mi)                              \
      _Pragma("unroll") for (int kk=0;kk<2;++kk)                            \
        afr[mi][kk] = ldsA(BUF, mi+4, kk);                                  \
    if ((S3T) >= 0) stage((S3T), (S3H));                                    \
    BARRIER();                                                              \
    MF16(afr, bfr1, 4, 2);                                                  \
    BARRIER();                                                              \
    _Pragma("unroll") for (int nj=0;nj<2;++nj)                              \
      _Pragma("unroll") for (int kk=0;kk<2;++kk)                            \
        bfr0[nj][kk] = ldsB(BUF, nj, kk);                                   \
    if ((S4T) >= 0) stage((S4T), (S4H));                                    \
    VMW(VN);                                                                \
    BARRIER();                                                              \
    MF16(afr, bfr0, 4, 0);                                                  \
    BARRIER();                                                              \
  } while(0)

template<int MODE>
__global__ __launch_bounds__(512, 2) void gemm256_kernel(
    const u16* __restrict__ A, const u16* __restrict__ BT,
    float* __restrict__ C,
    u16* __restrict__ Qp, u16* __restrict__ Kp, u16* __restrict__ Vp,
    int M, int N, int K, int nxtile)
{
  __shared__ __align__(16) u16 As[2][16384];
  __shared__ __align__(16) u16 Bs[2][16384];

  int cpx = gridDim.x >> 3;
  int wg  = blockIdx.x;
  int swz = (wg & 7)*cpx + (wg >> 3);
  const int bx = swz % nxtile, by = swz / nxtile;
  const int m0 = by*256, n0 = bx*256;
  const int tid = threadIdx.x;
  const int lane = tid & 63, w = tid >> 6;
  const int wr = w >> 2, wc = w & 3;

  f32x4 acc[8][4];
  #pragma unroll
  for (int i=0;i<8;i++)
    #pragma unroll
    for (int j=0;j<4;j++) acc[i][j] = (f32x4)0.f;

  auto stage = [&](int t, int h){
    int buf = t & 1;
    int hb  = h & 1;
    bool isA = (h < 2);
    const u16* src = isA ? A : BT;
    int r0g = isA ? m0 : n0;
    u16* lb = isA ? &As[buf][0] : &Bs[buf][0];
    int kb = t*64;
    #pragma unroll
    for (int q = 0; q < 2; ++q) {
      int rit  = hb*128 + q*64 + (tid>>3);
      int colb = ((tid&7)*16) ^ ((rit&7)<<4);
      const u16* g = src + (size_t)(r0g + rit)*K + kb + (colb>>1);
      gload_lds16(g, lb + (hb*128 + q*64)*64 + tid*8);
    }
  };
  auto ldsA = [&](int buf, int mi, int kk)->bf16x8 {
    int r = wr*128 + mi*16 + (lane&15);
    int chunk = (kk*4 + (lane>>4)) ^ (r&7);
    return *(const bf16x8*)&As[buf][r*64 + chunk*8];
  };
  auto ldsB = [&](int buf, int nj, int kk)->bf16x8 {
    int r = wc*64 + nj*16 + (lane&15);
    int chunk = (kk*4 + (lane>>4)) ^ (r&7);
    return *(const bf16x8*)&Bs[buf][r*64 + chunk*8];
  };

  bf16x8 afr[4][2], bfr0[2][2], bfr1[2][2];

  const int NT = K >> 6;                       // 16 for K=1024
  stage(0,0); stage(0,1); stage(0,2); stage(0,3);
  stage(1,0);
  VMW(2);
  BARRIER();

  for (int j = 0; j < NT/2 - 1; ++j) {
    int t1s = 2*j+1, t2s = 2*j+2, t3s = 2*j+3;
    TILE_STEP(0, t1s,1, t1s,2, t1s,3, t2s,0, 2);
    TILE_STEP(1, t2s,1, t2s,2, t2s,3, t3s,0, 2);
  }
  {
    int tl = NT-1;
    TILE_STEP(0, tl,1, tl,2, tl,3, -1,0, 0);
    TILE_STEP(1, -1,0, -1,0, -1,0, -1,0, 0);
  }

  if (MODE == 0) {
    #pragma unroll
    for (int mi=0; mi<8; mi++)
      #pragma unroll
      for (int nj=0; nj<4; nj++){
        int row = m0 + wr*128 + mi*16 + ((lane>>4)<<2);
        int col = n0 + wc*64 + nj*16 + (lane&15);
        #pragma unroll
        for (int r=0;r<4;r++)
          C[(size_t)(row+r)*N + col] = acc[mi][nj][r];
      }
  } else {
    int mat = n0 >> 10;
    u16* dst = (mat==0) ? Qp : (mat==1 ? Kp : Vp);
    float sc = (mat==0) ? 0.125f : 1.0f;
    int cc0 = n0 & 1023;
    #pragma unroll
    for (int mi=0; mi<8; mi++)
      #pragma unroll
      for (int nj=0; nj<4; nj++){
        int row = m0 + wr*128 + mi*16 + ((lane>>4)<<2);
        int col = cc0 + wc*64 + nj*16 + (lane&15);
        #pragma unroll
        for (int r=0;r<4;r++)
          dst[(size_t)(row+r)*1024 + col] = f2b(acc[mi][nj][r]*sc);
      }
  }
}

// ---------------- K1: all-level max hierarchy (sq from q, spank from k) ----------
__global__ __launch_bounds__(256) void spanmax_kernel(
    const u16* __restrict__ qb, const u16* __restrict__ kb,
    u16* __restrict__ sqArr, u16* __restrict__ spank)
{
  __shared__ __align__(16) u16 lsh[63*64];
  int bid = blockIdx.x;
  int tensor = bid >> 8;
  int idx = bid & 255;
  int bhh = idx >> 1, half = idx & 1;
  int b = bhh >> 4, h = bhh & 15;
  const u16* src = tensor ? kb : qb;
  u16* dst = tensor ? spank : sqArr;
  int tid = threadIdx.x;
  int m5 = tid >> 3, oct = tid & 7;
  int tbase = half*1024 + m5*32;
  unsigned gbase = ((unsigned)(b*2048 + tbase))*1024u + (unsigned)h*64u + (unsigned)oct*8u;

  float c1[8],c2[8],c3[8],c4[8],c5[8],f[8];
  #pragma unroll
  for (int jj=0;jj<32;jj++){
    uint4 v = *(const uint4*)(src + gbase + (unsigned)jj*1024u);
    up8(v,f);
    if ((jj&1)==0) { cp8(c1,f); }
    else {
      mx8(c1,f);
      { unsigned grow = LO[0] + (unsigned)bhh*1024u + (unsigned)((tbase+jj)>>1);
        *(uint4*)(dst + grow*64u + oct*8u) = pk8(c1); }
      if ((jj&3)==1) cp8(c2,c1); else mx8(c2,c1);
      if ((jj&3)==3){
        unsigned grow = LO[1] + (unsigned)bhh*512u + (unsigned)((tbase+jj)>>2);
        *(uint4*)(dst + grow*64u + oct*8u) = pk8(c2);
        if ((jj&7)==3) cp8(c3,c2); else mx8(c3,c2);
        if ((jj&7)==7){
          unsigned g3 = LO[2] + (unsigned)bhh*256u + (unsigned)((tbase+jj)>>3);
          *(uint4*)(dst + g3*64u + oct*8u) = pk8(c3);
          if ((jj&15)==7) cp8(c4,c3); else mx8(c4,c3);
          if ((jj&15)==15){
            unsigned g4 = LO[3] + (unsigned)bhh*128u + (unsigned)((tbase+jj)>>4);
            *(uint4*)(dst + g4*64u + oct*8u) = pk8(c4);
            if (jj==15) cp8(c5,c4); else mx8(c5,c4);
            if (jj==31){
              unsigned g5 = LO[4] + (unsigned)bhh*64u + (unsigned)((tbase+jj)>>5);
              uint4 pk = pk8(c5);
              *(uint4*)(dst + g5*64u + oct*8u) = pk;
              *(uint4*)&lsh[(m5*8+oct)*8] = pk;
            }
          }
        }
      }
    }
  }
  __syncthreads();
  int g = tid>>3;
  #define TREE(LV, INOFF, OUTOFF, NR)                                        \
    if (g < (NR)) {                                                          \
      float a[8], bb[8];                                                     \
      up8(*(const uint4*)&lsh[(((INOFF)+2*g)*8+oct)*8], a);                  \
      up8(*(const uint4*)&lsh[(((INOFF)+2*g+1)*8+oct)*8], bb);               \
      mx8(a,bb);                                                             \
      uint4 pk = pk8(a);                                                     \
      unsigned grow = LO[LV-1] + (unsigned)bhh*(2048u>>LV)                   \
                    + (unsigned)(half*(1024>>LV)) + (unsigned)g;             \
      *(uint4*)(dst + grow*64u + oct*8u) = pk;                               \
      if ((LV)<10) *(uint4*)&lsh[(((OUTOFF)+g)*8+oct)*8] = pk;               \
    }                                                                        \
    __syncthreads();
  TREE(6,0,32,16)
  TREE(7,32,48,8)
  TREE(8,48,56,4)
  TREE(9,56,60,2)
  TREE(10,60,62,1)
  #undef TREE
}

// ---------------- K2: fused span attention, levels 1-8 + partials 9/10 -----------
template<int L>
__device__ __forceinline__ void span_level(
    int tid, int bhh, int seg, unsigned gbase,
    const float* kreg, const u16* __restrict__ sq, const u16* __restrict__ vb,
    u16* __restrict__ spanv, float* e_sh, float* csum, float* wred, float* pvw)
{
  const int j = tid;
  const int wv = tid >> 6;
  unsigned srow = LO[L-1] + (unsigned)bhh*(2048u>>L)
                + (unsigned)(seg*(256>>L)) + (unsigned)(j>>L);
  float d = dotrow(kreg, sq + (size_t)srow*64u);

  float M = d;
  if constexpr (L<=6) {
    #pragma unroll
    for (int o=1;o<(1<<L);o<<=1) M = fmaxf(M, __shfl_xor(M,o));
  } else {
    #pragma unroll
    for (int o=1;o<64;o<<=1) M = fmaxf(M, __shfl_xor(M,o));
    if ((tid&63)==0) wred[wv] = M;
    __syncthreads();
    if constexpr (L==7) M = fmaxf(wred[wv&2], wred[(wv&2)|1]);
    else M = fmaxf(fmaxf(wred[0],wred[1]),fmaxf(wred[2],wred[3]));
    __syncthreads();
  }
  float e = __expf(d - M);
  e_sh[j] = e;
  float S = e;
  if constexpr (L<=6) {
    #pragma unroll
    for (int o=1;o<(1<<L);o<<=1) S += __shfl_xor(S,o);
  } else {
    #pragma unroll
    for (int o=1;o<64;o<<=1) S += __shfl_xor(S,o);
    if ((tid&63)==0) wred[wv] = S;
    __syncthreads();
    if constexpr (L==7) S = wred[wv&2] + wred[(wv&2)|1];
    else S = wred[0]+wred[1]+wred[2]+wred[3];
    __syncthreads();
  }
  if constexpr (L<=2) { if ((j&((1<<L)-1))==0) csum[j>>L] = S; }
  __syncthreads();

  if constexpr (L<=2) {
    #pragma unroll
    for (int p0=0; p0<(256>>L)*8; p0+=256){
      int p = p0 + tid;
      int c = p>>3, oct = p&7;
      float fa[8] = {0,0,0,0,0,0,0,0};
      #pragma unroll
      for (int jj=0;jj<(1<<L);jj++){
        int row = (c<<L)|jj;
        fma8(fa, e_sh[row], *(const uint4*)(vb + gbase + (unsigned)row*1024u + oct*8));
      }
      float inv = 1.f/csum[c];
      #pragma unroll
      for (int i=0;i<8;i++) fa[i] *= inv;
      unsigned grow = LO[L-1] + (unsigned)bhh*(2048u>>L) + (unsigned)(seg*(256>>L)) + c;
      *(uint4*)(spanv + grow*64u + oct*8u) = pk8(fa);
    }
  } else {
    int u = tid & ((1<<L)-1);
    int c = tid >> L;
    int oct = u & 7;
    int r0 = (u>>3)*8;
    float fa[8] = {0,0,0,0,0,0,0,0};
    #pragma unroll
    for (int jj=0;jj<8;jj++){
      int row = (c<<L) + r0 + jj;
      fma8(fa, e_sh[row], *(const uint4*)(vb + gbase + (unsigned)row*1024u + oct*8));
    }
    #pragma unroll
    for (int o=8; o<(1<<(L<=6?L:6)); o<<=1)
      #pragma unroll
      for (int i=0;i<8;i++) fa[i] += __shfl_xor(fa[i],o);
    if constexpr (L>=7){
      if ((tid&63)<8)
        #pragma unroll
        for (int i=0;i<8;i++) pvw[(wv*8+oct)*8+i] = fa[i];
      __syncthreads();
      if constexpr (L==7){
        if ((tid&127)<8)
          #pragma unroll
          for (int i=0;i<8;i++) fa[i] += pvw[(((wv)|1)*8+oct)*8+i];
      } else {
        if (tid<8)
          #pragma unroll
          for (int i=0;i<8;i++) fa[i] += pvw[(1*8+oct)*8+i]+pvw[(2*8+oct)*8+i]+pvw[(3*8+oct)*8+i];
      }
    }
    bool writer = (L<7) ? (u<8) : ((L==7) ? ((tid&127)<8) : (tid<8));
    if (writer){
      float inv = 1.f/S;
      #pragma unroll
      for (int i=0;i<8;i++) fa[i] *= inv;
      unsigned grow = LO[L-1] + (unsigned)bhh*(2048u>>L) + (unsigned)(seg*(256>>L)) + c;
      *(uint4*)(spanv + grow*64u + oct*8u) = pk8(fa);
    }
  }
  __syncthreads();
}

__device__ __forceinline__ void partial_level(
    int tid, float d, unsigned gbase, const u16* __restrict__ vb,
    float* e_sh, float* wred, float* pvw, float* __restrict__ entry)
{
  const int wv = tid >> 6;
  float M = d;
  #pragma unroll
  for (int o=1;o<64;o<<=1) M = fmaxf(M, __shfl_xor(M,o));
  if ((tid&63)==0) wred[wv] = M;
  __syncthreads();
  M = fmaxf(fmaxf(wred[0],wred[1]), fmaxf(wred[2],wred[3]));
  __syncthreads();
  float e = __expf(d - M);
  e_sh[tid] = e;
  float S = e;
  #pragma unroll
  for (int o=1;o<64;o<<=1) S += __shfl_xor(S,o);
  if ((tid&63)==0) wred[wv] = S;
  __syncthreads();
  S = wred[0]+wred[1]+wred[2]+wred[3];

  int oct = tid&7, r0 = (tid>>3)*8;
  float fa[8] = {0,0,0,0,0,0,0,0};
  #pragma unroll
  for (int jj=0;jj<8;jj++){
    int row = r0+jj;
    fma8(fa, e_sh[row], *(const uint4*)(vb + gbase + (unsigned)row*1024u + oct*8));
  }
  #pragma unroll
  for (int o=8;o<64;o<<=1)
    #pragma unroll
    for (int i=0;i<8;i++) fa[i] += __shfl_xor(fa[i],o);
  __syncthreads();
  if ((tid&63)<8)
    #pragma unroll
    for (int i=0;i<8;i++) pvw[(wv*8+oct)*8+i] = fa[i];
  __syncthreads();
  if (tid<8){
    #pragma unroll
    for (int i=0;i<8;i++)
      fa[i] += pvw[(1*8+oct)*8+i]+pvw[(2*8+oct)*8+i]+pvw[(3*8+oct)*8+i];
    #pragma unroll
    for (int i=0;i<8;i++) entry[oct*8+i] = fa[i];
  }
  if (tid==0){ entry[64]=M; entry[65]=S; }
  __syncthreads();
}

__global__ __launch_bounds__(256) void spanv_kernel(
    const u16* __restrict__ kb, const u16* __restrict__ vb,
    const u16* __restrict__ sq, u16* __restrict__ spanv,
    float* __restrict__ parts)
{
  __shared__ __align__(16) u16 ksh[256*64];
  __shared__ float e_sh[256];
  __shared__ float csum[128];
  __shared__ float wred[4];
  __shared__ float pvw[4*8*8];

  int bid = blockIdx.x;
  int bhh = bid>>3, seg = bid&7;
  int b = bhh>>4, h = bhh&15;
  int tid = threadIdx.x;
  unsigned gbase = ((unsigned)(b*2048 + seg*256))*1024u + (unsigned)h*64u;

  #pragma unroll
  for (int it=0; it<8; ++it){
    int r = it*32 + (tid>>3);
    int c = tid&7;
    uint4 v = *(const uint4*)(kb + gbase + (unsigned)r*1024u + c*8);
    *(uint4*)&ksh[(r*8 + (c^(r&7)))*8] = v;
  }
  __syncthreads();
  float kreg[64];
  #pragma unroll
  for (int c=0;c<8;c++){
    uint4 v = *(const uint4*)&ksh[(tid*8 + (c^(tid&7)))*8];
    up8(v, kreg+c*8);
  }

  span_level<1>(tid,bhh,seg,gbase,kreg,sq,vb,spanv,e_sh,csum,wred,pvw);
  span_level<2>(tid,bhh,seg,gbase,kreg,sq,vb,spanv,e_sh,csum,wred,pvw);
  span_level<3>(tid,bhh,seg,gbase,kreg,sq,vb,spanv,e_sh,csum,wred,pvw);
  span_level<4>(tid,bhh,seg,gbase,kreg,sq,vb,spanv,e_sh,csum,wred,pvw);
  span_level<5>(tid,bhh,seg,gbase,kreg,sq,vb,spanv,e_sh,csum,wred,pvw);
  span_level<6>(tid,bhh,seg,gbase,kreg,sq,vb,spanv,e_sh,csum,wred,pvw);
  span_level<7>(tid,bhh,seg,gbase,kreg,sq,vb,spanv,e_sh,csum,wred,pvw);
  span_level<8>(tid,bhh,seg,gbase,kreg,sq,vb,spanv,e_sh,csum,wred,pvw);

  float d9  = dotrow(kreg, sq + (size_t)(LO[8] + (unsigned)bhh*4u + (unsigned)(seg>>1))*64u);
  float d10 = dotrow(kreg, sq + (size_t)(LO[9] + (unsigned)bhh*2u + (unsigned)(seg>>2))*64u);
  partial_level(tid, d9,  gbase, vb, e_sh, wred, pvw, parts + (size_t)(bhh*8+seg)*68u);
  partial_level(tid, d10, gbase, vb, e_sh, wred, pvw, parts + (size_t)(1024 + bhh*8+seg)*68u);
}

// ---------------- K3: combine level 9/10 partials ----------------
__global__ __launch_bounds__(64) void spancomb_kernel(
    const float* __restrict__ parts, u16* __restrict__ spanv)
{
  int bid = blockIdx.x, d = threadIdx.x;
  if (bid < 512){
    int bhh = bid>>2, m9 = bid&3;
    const float* p0 = parts + (size_t)(bhh*8 + m9*2)*68u;
    const float* p1 = p0 + 68;
    float m0=p0[64], s0=p0[65], m1=p1[64], s1=p1[65];
    float M = fmaxf(m0,m1);
    float e0 = __expf(m0-M), e1 = __expf(m1-M);
    float S = s0*e0 + s1*e1;
    float A = p0[d]*e0 + p1[d]*e1;
    unsigned grow = LO[8] + (unsigned)bhh*4u + (unsigned)m9;
    spanv[grow*64u + d] = f2b(A/S);
  } else {
    int cid = bid-512; int bhh = cid>>1, m10 = cid&1;
    const float* pp = parts + (size_t)(1024 + bhh*8 + m10*4)*68u;
    float M = -1e30f;
    #pragma unroll
    for (int p=0;p<4;p++) M = fmaxf(M, pp[p*68+64]);
    float S=0.f, A=0.f;
    #pragma unroll
    for (int p=0;p<4;p++){
      float sc = __expf(pp[p*68+64]-M);
      S += pp[p*68+65]*sc;
      A += pp[p*68+d]*sc;
    }
    unsigned grow = LO[9] + (unsigned)bhh*2u + (unsigned)m10;
    spanv[grow*64u + d] = f2b(A/S);
  }
}

// ---------------- merge: 2 threads per (b,t,h), 32 dims each ----------------
__device__ __forceinline__ float dot32(const u16* __restrict__ row, const float* __restrict__ qd){
  float s = 0.f;
  #pragma unroll
  for (int j=0;j<4;j++){
    uint4 kv = *(const uint4*)(row + j*8);
    s += qd[j*8+0]*bl(kv.x) + qd[j*8+1]*bh(kv.x);
    s += qd[j*8+2]*bl(kv.y) + qd[j*8+3]*bh(kv.y);
    s += qd[j*8+4]*bl(kv.z) + qd[j*8+5]*bh(kv.z);
    s += qd[j*8+6]*bl(kv.w) + qd[j*8+7]*bh(kv.w);
  }
  return s;
}
__device__ __forceinline__ void axpy32(float w, const u16* __restrict__ row, float* __restrict__ acc){
  #pragma unroll
  for (int j=0;j<4;j++){
    uint4 kv = *(const uint4*)(row + j*8);
    acc[j*8+0] += w*bl(kv.x); acc[j*8+1] += w*bh(kv.x);
    acc[j*8+2] += w*bl(kv.y); acc[j*8+3] += w*bh(kv.y);
    acc[j*8+4] += w*bl(kv.z); acc[j*8+5] += w*bh(kv.z);
    acc[j*8+6] += w*bl(kv.w); acc[j*8+7] += w*bh(kv.w);
  }
}

__global__ __launch_bounds__(256) void merge_kernel(
    const u16* __restrict__ q, const u16* __restrict__ k, const u16* __restrict__ v,
    const u16* __restrict__ spank, const u16* __restrict__ spanv,
    u16* __restrict__ merged)
{
  int tid  = threadIdx.x;
  int eidx = blockIdx.x*128 + (tid>>1);
  int half = tid & 1;
  int h = eidx & 15;
  int t = (eidx >> 4) & (T_-1);
  unsigned qrow = (unsigned)eidx*64u + (unsigned)half*32u;
  int b = eidx >> 15;
  int bhh = b*16 + h;

  float qd[32];
  {
    const u16* qr = q + qrow;
    #pragma unroll
    for (int j=0;j<4;j++){
      uint4 kv = *(const uint4*)(qr + j*8);
      qd[j*8+0]=bl(kv.x); qd[j*8+1]=bh(kv.x);
      qd[j*8+2]=bl(kv.y); qd[j*8+3]=bh(kv.y);
      qd[j*8+4]=bl(kv.z); qd[j*8+5]=bh(kv.z);
      qd[j*8+6]=bl(kv.w); qd[j*8+7]=bh(kv.w);
    }
  }

  float lg[12];
  unsigned off[11];
  unsigned msk = 0;
  { float p = dot32(k + qrow, qd); lg[0] = p + __shfl_xor(p, 1); }

  #pragma unroll
  for (int l=0; l<LOGL; l++){
    const int c = 1<<l;
    bool mk = false; unsigned o = 0;
    if (t >= c) {
      int m = (t - c) >> l;
      if ((m & 1) == 0) {
        mk = true;
        if (l == 0) {
          o = qrow - 1024u;
        } else {
          unsigned row = LO[l-1] + (unsigned)bhh*(2048u>>l) + (unsigned)m;
          o = row*64u + (unsigned)half*32u;
        }
      }
    }
    float L = -1e30f;
    if (mk) {
      const u16* row = (l==0) ? (k + o) : (spank + o);
      float p = dot32(row, qd);
      L = p + __shfl_xor(p, 1);
    }
    lg[l+1] = L;
    off[l] = o;
    if (mk) msk |= (1u<<l);
  }

  float M = lg[0];
  #pragma unroll
  for (int i=1;i<12;i++) M = fmaxf(M, lg[i]);
  float w[12]; float s = 0.f;
  #pragma unroll
  for (int i=0;i<12;i++){ w[i] = __expf(lg[i]-M); s += w[i]; }

  float acc[32];
  #pragma unroll
  for (int d=0;d<32;d++) acc[d] = 0.f;
  axpy32(w[0], v + qrow, acc);
  #pragma unroll
  for (int l=0; l<LOGL; l++){
    if (msk & (1u<<l)) {
      const u16* row = (l==0) ? (v + off[l]) : (spanv + off[l]);
      axpy32(w[l+1], row, acc);
    }
  }

  float inv = 1.f/s;
  u16 ob[32];
  #pragma unroll
  for (int d=0;d<32;d++) ob[d] = f2b(acc[d]*inv);
  u16* orow = merged + qrow;
  *(uint4*)(orow)      = *(uint4*)(ob);
  *(uint4*)(orow + 8)  = *(uint4*)(ob+8);
  *(uint4*)(orow + 16) = *(uint4*)(ob+16);
  *(uint4*)(orow + 24) = *(uint4*)(ob+24);
}

// ---------------- launch ----------------
extern "C" void kernel_launch(void* const* d_in, const int* in_sizes, int n_in,
                              void* d_out, int out_size, void* d_ws, size_t ws_size,
                              hipStream_t stream) {
  (void)in_sizes; (void)n_in; (void)out_size; (void)ws_size;
  const float* x  = (const float*)d_in[0];
  const float* Wq = (const float*)d_in[1];
  const float* Wk = (const float*)d_in[2];
  const float* Wv = (const float*)d_in[3];
  const float* Wo = (const float*)d_in[4];
  float* out = (float*)d_out;

  uint8_t* w = (uint8_t*)d_ws;
  u16* xb     = (u16*)(w);                   // 32 MB (reused as merged)
  u16* qb     = (u16*)(w + 33554432ull);     // 32 MB
  u16* kb     = (u16*)(w + 67108864ull);     // 32 MB
  u16* vb     = (u16*)(w + 100663296ull);    // 32 MB
  u16* spank  = (u16*)(w + 134217728ull);    // 32 MB
  u16* spanv  = (u16*)(w + 167772160ull);    // 32 MB
  u16* wqkvT  = (u16*)(w + 201326592ull);    // 6 MB
  u16* woT    = (u16*)(w + 207618048ull);    // 2 MB
  // scratch in d_out (dead until final gemm overwrites it):
  u16*   sqArr = (u16*)d_out;                             // 33.5 MB
  float* parts = (float*)((uint8_t*)d_out + 50331648ull); // 557 KB @ +48MB

  prep_kernel<<<9216, 256, 0, stream>>>(x, Wq, Wk, Wv, Wo, xb, wqkvT, woT);

  gemm256_kernel<1><<<768, 512, 0, stream>>>(xb, wqkvT, nullptr, qb, kb, vb,
                                             16384, 3072, 1024, 12);

  spanmax_kernel<<<512, 256, 0, stream>>>(qb, kb, sqArr, spank);
  spanv_kernel<<<1024, 256, 0, stream>>>(kb, vb, sqArr, spanv, parts);
  spancomb_kernel<<<768, 64, 0, stream>>>(parts, spanv);

  merge_kernel<<<2048, 256, 0, stream>>>(qb, kb, vb, spank, spanv, xb /*merged*/);

  gemm256_kernel<0><<<256, 512, 0, stream>>>(xb, woT, out, nullptr, nullptr, nullptr,
                                             16384, 1024, 1024, 4);
}